// Round 2
// baseline (764.772 us; speedup 1.0000x reference)
//
#include <hip/hip_runtime.h>
#include <hip/hip_bf16.h>
#include <math.h>

#define N_  4
#define C_  512
#define H_  64
#define W_  64
#define HW_ 4096
#define CR_ 64
#define NC_ 64
#define EPSV 1e-5f

typedef __attribute__((ext_vector_type(8))) __bf16 bf16x8;
typedef __attribute__((ext_vector_type(4))) float f32x4;
typedef __hip_bfloat16 bf16s;

__device__ __forceinline__ unsigned short bfb(float f) {
    union { bf16s h; unsigned short u; } cv;
    cv.h = __float2bfloat16(f);
    return cv.u;
}

// XOR-swizzled element offset for a [64][64] bf16 LDS tile (128 B rows,
// 8 chunks of 16 B). chunk' = chunk ^ (row&7) -> conflict-free b128 access
// for both row-parallel reads (lr varies) and chunk-parallel writes.
__device__ __forceinline__ int swz8(int row, int ch) {
    return row * 64 + ((ch ^ (row & 7)) << 3);
}

// ---------------------------------------------------------------------------
// x [n][c][hw] fp32 -> xbT [n][hw][c] bf16
// ---------------------------------------------------------------------------
__global__ __launch_bounds__(256) void k_xpose(
    const float* __restrict__ x, bf16s* __restrict__ xbT)
{
    __shared__ float xs[64][65];
    const int tid = threadIdx.x;
    const int n = blockIdx.z, c0 = blockIdx.y * 64, p0 = blockIdx.x * 64;
    for (int e = tid; e < 4096; e += 256) {
        int ci = e >> 6, pi = e & 63;
        xs[ci][pi] = x[((size_t)(n*C_ + c0 + ci))*HW_ + p0 + pi];
    }
    __syncthreads();
    for (int e = tid; e < 4096; e += 256) {
        int pi = e >> 6, ci = e & 63;
        xbT[((size_t)n*HW_ + p0 + pi)*C_ + c0 + ci] = __float2bfloat16(xs[ci][pi]);
    }
}

// w [o][c][3][3] fp32 -> wb [o][tap][c] bf16
__global__ __launch_bounds__(256) void k_wprep(
    const float* __restrict__ w, bf16s* __restrict__ wb)
{
    int e = blockIdx.x * 256 + threadIdx.x;           // < 512*9*512
    int c = e & 511; int r = e >> 9;
    int tap = r % 9; int o = r / 9;
    wb[e] = __float2bfloat16(w[((size_t)o*C_ + c)*9 + tap]);
}

// flat fp32 -> bf16 cast
__global__ __launch_bounds__(256) void k_wcast(
    const float* __restrict__ in, bf16s* __restrict__ out, int nElem)
{
    int e = blockIdx.x * 256 + threadIdx.x;
    if (e < nElem) out[e] = __float2bfloat16(in[e]);
}

// ---------------------------------------------------------------------------
// conv3x3 + BN + LReLU implicit-GEMM MFMA.
// mode 0 (PAM): writes feat fp32 [c][p] AND featT bf16 [p][c]
// mode 1 (CAM): writes featT only + atomicAdd per-channel activation sums
// T14: per-(c0,dyi) tiles register-prefetched one iteration ahead so global
// latency hides under the 48-MFMA compute phase (grid-capped at 2 blk/CU,
// so the extra ~36 VGPRs are free).
// ---------------------------------------------------------------------------
__global__ __launch_bounds__(256) void k_conv3x3_mfma(
    const bf16s* __restrict__ xbT, const bf16s* __restrict__ wb,
    const float* __restrict__ gamma, const float* __restrict__ beta,
    const float* __restrict__ mean, const float* __restrict__ var,
    float* __restrict__ out, bf16s* __restrict__ featT,
    float* __restrict__ csum, int mode)
{
    __shared__ bf16s aL[3][128][40];
    __shared__ bf16s bL[132][40];            // [ry*66+xi][ch]
    const int tid = threadIdx.x;
    const int n  = blockIdx.z;
    const int o0 = blockIdx.y * 128;
    const int pt = blockIdx.x;
    const int y0 = pt * 2;
    const int lane = tid & 63;
    const int wid  = tid >> 6;
    const int wr = wid >> 1, wc = wid & 1;
    const int lr = lane & 15, cb = lane >> 4;

    f32x4 acc[4][4];
#pragma unroll
    for (int i = 0; i < 4; ++i)
#pragma unroll
        for (int j = 0; j < 4; ++j) acc[i][j] = (f32x4){0.f,0.f,0.f,0.f};

    int4 pA[6], pB[3];
    auto issueA = [&](int c0, int dyi) {
#pragma unroll
        for (int k = 0; k < 6; ++k) {
            int e = tid + k*256;
            int cb2 = e & 3, o = (e >> 2) & 127, dxi = e >> 9;
            pA[k] = *(const int4*)(wb +
                ((size_t)(o0 + o)*9 + dyi*3 + dxi)*C_ + c0 + cb2*8);
        }
    };
    auto issueB = [&](int c0, int dyi) {
#pragma unroll
        for (int k = 0; k < 3; ++k) {
            int e = tid + k*256;
            int4 v = {0,0,0,0};
            if (e < 528) {
                int cb2 = e & 3, t = e >> 2;
                int xi = t % 66, ry = t / 66;
                int row = y0 + dyi - 1 + ry;
                int xc  = xi - 1;
                if (row >= 0 && row < H_ && xc >= 0 && xc < W_)
                    v = *(const int4*)(xbT +
                        ((size_t)n*HW_ + row*W_ + xc)*C_ + c0 + cb2*8);
            }
            pB[k] = v;
        }
    };

    issueA(0, 0); issueB(0, 0);
    int c0 = 0, dyi = 0;
    for (int it = 0; it < 48; ++it) {
        // write prefetched regs -> LDS (compiler inserts the vmcnt wait)
#pragma unroll
        for (int k = 0; k < 6; ++k) {
            int e = tid + k*256;
            int cb2 = e & 3, o = (e >> 2) & 127, dxi = e >> 9;
            *(int4*)&aL[dxi][o][cb2*8] = pA[k];
        }
#pragma unroll
        for (int k = 0; k < 3; ++k) {
            int e = tid + k*256;
            if (e < 528)
                *(int4*)&bL[e >> 2][(e & 3)*8] = pB[k];
        }
        __syncthreads();                     // tiles(it) visible
        int nd = dyi + 1, nc = c0;
        if (nd == 3) { nd = 0; nc += 32; }
        if (it < 47) { issueA(nc, nd); issueB(nc, nd); }  // overlap w/ MFMA
#pragma unroll
        for (int dxi = 0; dxi < 3; ++dxi) {
            bf16x8 af[4], bfv[4];
#pragma unroll
            for (int fm = 0; fm < 4; ++fm)
                af[fm] = *(const bf16x8*)&aL[dxi][wr*64 + fm*16 + lr][cb*8];
#pragma unroll
            for (int fn = 0; fn < 4; ++fn) {
                int pg = wc*64 + fn*16 + lr;
                int ry = pg >> 6, xc = pg & 63;
                bfv[fn] = *(const bf16x8*)&bL[ry*66 + xc + dxi][cb*8];
            }
#pragma unroll
            for (int fm = 0; fm < 4; ++fm)
#pragma unroll
                for (int fn = 0; fn < 4; ++fn)
                    acc[fm][fn] = __builtin_amdgcn_mfma_f32_16x16x32_bf16(
                        af[fm], bfv[fn], acc[fm][fn], 0, 0, 0);
        }
        __syncthreads();                     // readers(it) done
        c0 = nc; dyi = nd;
    }
#pragma unroll
    for (int fm = 0; fm < 4; ++fm) {
        float sc[4], sh[4];
        const int obase = o0 + wr*64 + fm*16 + cb*4;
#pragma unroll
        for (int r = 0; r < 4; ++r) {
            int o = obase + r;
            sc[r] = gamma[o] * rsqrtf(var[o] + EPSV);
            sh[r] = beta[o] - mean[o]*sc[r];
        }
        float ps[4] = {0.f, 0.f, 0.f, 0.f};
#pragma unroll
        for (int fn = 0; fn < 4; ++fn) {
            int pg = wc*64 + fn*16 + lr;
            int p  = pt*128 + pg;
            float vv[4];
#pragma unroll
            for (int r = 0; r < 4; ++r) {
                float t = fmaf(acc[fm][fn][r], sc[r], sh[r]);
                vv[r] = t > 0.f ? t : 0.2f*t;
                if (mode == 0)
                    out[((size_t)(n*C_ + obase + r))*HW_ + p] = vv[r];
                else
                    ps[r] += vv[r];
            }
            uint2 u;
            u.x = (unsigned)bfb(vv[0]) | ((unsigned)bfb(vv[1]) << 16);
            u.y = (unsigned)bfb(vv[2]) | ((unsigned)bfb(vv[3]) << 16);
            *(uint2*)&featT[((size_t)n*HW_ + p)*C_ + obase] = u;
        }
        if (mode != 0) {
            // per-channel activation sums (fp32-exact source); lanes lr=0..15
            // share the same channel -> shuffle-reduce then 1 atomic
#pragma unroll
            for (int r = 0; r < 4; ++r) {
                float s = ps[r];
                s += __shfl_xor(s, 1);
                s += __shfl_xor(s, 2);
                s += __shfl_xor(s, 4);
                s += __shfl_xor(s, 8);
                if (lr == 0) atomicAdd(&csum[n*C_ + obase + r], s);
            }
        }
    }
}

// ---------------------------------------------------------------------------
// bf16 MFMA GEMM: out[o][p] = (A[o][:] * scale?) . Bt[p][:] + bias[o]
// mode 0: fp32 out [n][O][p]; mode 1: bf16 out [n][p][O]; mode 2: bf16 [n][O][p]
// grid (HW/256, O/64, n), block 256. T14 register-prefetch, pv-style.
// ---------------------------------------------------------------------------
__global__ __launch_bounds__(256) void k_gemm(
    const bf16s* __restrict__ A, const bf16s* __restrict__ Bt,
    const float* __restrict__ bias, const float* __restrict__ scale,
    void* __restrict__ outp, int O, int mode)
{
    __shared__ bf16s aL[64][40];
    __shared__ bf16s bL[256][40];
    const int tid = threadIdx.x;
    const int n  = blockIdx.z;
    const int p0 = blockIdx.x * 256;
    const int o0 = blockIdx.y * 64;
    const int lane = tid & 63;
    const int wid  = tid >> 6;
    const int lr = lane & 15, cb = lane >> 4;
    const int arow = tid >> 2, ach = tid & 3;

    f32x4 acc[4][4];
#pragma unroll
    for (int i = 0; i < 4; ++i)
#pragma unroll
        for (int j = 0; j < 4; ++j) acc[i][j] = (f32x4){0.f,0.f,0.f,0.f};

    int4 pA, pB[4];
    float4 pS0, pS1;
    auto issue = [&](int c0) {
        pA = *(const int4*)&A[(size_t)(o0 + arow)*C_ + c0 + ach*8];
        if (scale) {
            pS0 = *(const float4*)&scale[(size_t)n*C_ + c0 + ach*8];
            pS1 = *(const float4*)&scale[(size_t)n*C_ + c0 + ach*8 + 4];
        }
#pragma unroll
        for (int k = 0; k < 4; ++k) {
            int e = tid + k*256; int row = e >> 2, ch = e & 3;
            pB[k] = *(const int4*)&Bt[((size_t)n*HW_ + p0 + row)*C_ + c0 + ch*8];
        }
    };

    issue(0);
    for (int c0 = 0; c0 < C_; c0 += 32) {
        if (scale) {
            const bf16s* sp = (const bf16s*)&pA;
            float sv[8] = {pS0.x, pS0.y, pS0.z, pS0.w,
                           pS1.x, pS1.y, pS1.z, pS1.w};
            bf16s tmp[8];
#pragma unroll
            for (int u = 0; u < 8; ++u)
                tmp[u] = __float2bfloat16(__bfloat162float(sp[u]) * sv[u]);
            *(int4*)&aL[arow][ach*8] = *(int4*)tmp;
        } else {
            *(int4*)&aL[arow][ach*8] = pA;
        }
#pragma unroll
        for (int k = 0; k < 4; ++k) {
            int e = tid + k*256; int row = e >> 2, ch = e & 3;
            *(int4*)&bL[row][ch*8] = pB[k];
        }
        __syncthreads();
        if (c0 + 32 < C_) issue(c0 + 32);    // overlap with MFMA below
        bf16x8 af[4], bfv[4];
#pragma unroll
        for (int fo = 0; fo < 4; ++fo)
            af[fo] = *(const bf16x8*)&aL[fo*16 + lr][cb*8];
#pragma unroll
        for (int fp = 0; fp < 4; ++fp)
            bfv[fp] = *(const bf16x8*)&bL[wid*64 + fp*16 + lr][cb*8];
#pragma unroll
        for (int fo = 0; fo < 4; ++fo)
#pragma unroll
            for (int fp = 0; fp < 4; ++fp)
                acc[fo][fp] = __builtin_amdgcn_mfma_f32_16x16x32_bf16(
                    af[fo], bfv[fp], acc[fo][fp], 0, 0, 0);
        __syncthreads();
    }
#pragma unroll
    for (int fo = 0; fo < 4; ++fo) {
        const int obase = o0 + fo*16 + cb*4;
        float bv[4];
#pragma unroll
        for (int r = 0; r < 4; ++r) bv[r] = bias[obase + r];
#pragma unroll
        for (int fp = 0; fp < 4; ++fp) {
            int p = p0 + wid*64 + fp*16 + lr;
            float v[4];
#pragma unroll
            for (int r = 0; r < 4; ++r) v[r] = acc[fo][fp][r] + bv[r];
            if (mode == 1) {
                uint2 u;
                u.x = (unsigned)bfb(v[0]) | ((unsigned)bfb(v[1]) << 16);
                u.y = (unsigned)bfb(v[2]) | ((unsigned)bfb(v[3]) << 16);
                *(uint2*)&((bf16s*)outp)[((size_t)n*HW_ + p)*O + (obase - o0)] = u;
            } else if (mode == 2) {
#pragma unroll
                for (int r = 0; r < 4; ++r)
                    ((bf16s*)outp)[((size_t)(n*O + obase + r))*HW_ + p] =
                        __float2bfloat16(v[r]);
            } else {
#pragma unroll
                for (int r = 0; r < 4; ++r)
                    ((float*)outp)[((size_t)(n*O + obase + r))*HW_ + p] = v[r];
            }
        }
    }
}

// ---------------------------------------------------------------------------
// pass A: partial rowm/rowl via S^T = mfma(K, Q), j-split x2 across grid.z.
// grid (64,4,2) remapped so XCD = lid%8 serves fixed (n, j-half).
// Swizzled LDS, Q-fragments hoisted to regs, K tile reg-prefetched.
// Writes partials rowm/rowl [jz][n][hw]; exact merge happens in k_pv_mfma.
// ---------------------------------------------------------------------------
__global__ __launch_bounds__(256) void k_rowstats_mfma(
    const bf16s* __restrict__ qb, const bf16s* __restrict__ kb,
    float* __restrict__ rowm, float* __restrict__ rowl)
{
    __shared__ bf16s qs[4096];
    __shared__ bf16s ks[4096];
    const int tid = threadIdx.x;
    const int lid = blockIdx.x + (blockIdx.y << 6) + (blockIdx.z << 8);
    const int n  = lid & 3;
    const int jz = (lid >> 2) & 1;
    const int i0 = (lid >> 3) << 6;
    const int lane = tid & 63;
    const int wid  = tid >> 6;
    const int lr = lane & 15, cb = lane >> 4;

    for (int e = tid; e < 512; e += 256) {
        int row = e >> 3, ch = e & 7;
        *(int4*)&qs[swz8(row, ch)] =
            *(const int4*)&qb[((size_t)n*HW_ + i0 + row)*CR_ + ch*8];
    }
    const int krow = tid >> 3, kch = tid & 7;
    const bf16s* kbase = kb + (size_t)n*HW_*CR_ + (size_t)jz*2048*CR_ + kch*8;
    int4 kreg0 = *(const int4*)(kbase + (size_t)krow*CR_);
    int4 kreg1 = *(const int4*)(kbase + (size_t)(krow + 32)*CR_);
    __syncthreads();
    bf16x8 bq[2];
#pragma unroll
    for (int kk = 0; kk < 2; ++kk)
        bq[kk] = *(const bf16x8*)&qs[swz8(wid*16 + lr, kk*4 + cb)];

    float m_t = -INFINITY, l_t = 0.f;
    for (int t = 0; t < 32; ++t) {
        __syncthreads();                       // S^T(t-1) readers done
        *(int4*)&ks[swz8(krow, kch)] = kreg0;
        *(int4*)&ks[swz8(krow + 32, kch)] = kreg1;
        if (t < 31) {                          // prefetch next K tile (T14)
            kreg0 = *(const int4*)(kbase + (size_t)((t+1)*64 + krow)*CR_);
            kreg1 = *(const int4*)(kbase + (size_t)((t+1)*64 + krow + 32)*CR_);
        }
        __syncthreads();
        f32x4 sv[4];
#pragma unroll
        for (int fj = 0; fj < 4; ++fj) {
            f32x4 s = (f32x4){0.f,0.f,0.f,0.f};
#pragma unroll
            for (int kk = 0; kk < 2; ++kk) {
                bf16x8 ak = *(const bf16x8*)&ks[swz8(fj*16 + lr, kk*4 + cb)];
                s = __builtin_amdgcn_mfma_f32_16x16x32_bf16(ak, bq[kk], s, 0, 0, 0);
            }
            sv[fj] = s;
        }
        float mx = m_t;
#pragma unroll
        for (int fj = 0; fj < 4; ++fj)
#pragma unroll
            for (int r = 0; r < 4; ++r) mx = fmaxf(mx, sv[fj][r]);
        float sum = 0.f;
#pragma unroll
        for (int fj = 0; fj < 4; ++fj)
#pragma unroll
            for (int r = 0; r < 4; ++r) sum += __expf(sv[fj][r] - mx);
        l_t = l_t * __expf(m_t - mx) + sum;
        m_t = mx;
    }
#pragma unroll
    for (int mask = 16; mask <= 32; mask <<= 1) {
        float mo = __shfl_xor(m_t, mask);
        float lo = __shfl_xor(l_t, mask);
        float m2 = fmaxf(m_t, mo);
        l_t = l_t * __expf(m_t - m2) + lo * __expf(mo - m2);
        m_t = m2;
    }
    if (cb == 0) {
        rowm[((size_t)jz*N_ + n)*HW_ + i0 + wid*16 + lr] = m_t;
        rowl[((size_t)jz*N_ + n)*HW_ + i0 + wid*16 + lr] = l_t;
    }
}

// ---------------------------------------------------------------------------
// pass B: block = 64 i x 128 c (4 c-chunks in grid). Per jt: S^T MFMA once
// (each wave 16 i x 64 j) -> exp -> P bf16 LDS -> PV MFMA (wave = 32c x 64i,
// V read DIRECT from global). Swizzled 16 KB LDS, Q hoisted to regs,
// K reg-prefetched one jt ahead, 2 barriers/iter.
// grid (64,4,4) remapped: XCD = lid%8 pinned to one n.
// ---------------------------------------------------------------------------
__global__ __launch_bounds__(256, 4) void k_pv_mfma(
    const bf16s* __restrict__ qb, const bf16s* __restrict__ kb,
    const bf16s* __restrict__ vb, const float* __restrict__ rowm,
    const float* __restrict__ rowl, const float* __restrict__ alpha,
    const float* __restrict__ feat, bf16s* __restrict__ featT)
{
    __shared__ bf16s ks[4096];
    __shared__ bf16s qps[4096];                  // Q staging, then P
    const int tid = threadIdx.x;
    const int lid = blockIdx.x + (blockIdx.y << 6) + (blockIdx.z << 8);
    const int k8  = lid & 7;
    const int n   = k8 >> 1;
    const int cc0 = (((lid >> 3) & 1) * 2 + (k8 & 1)) << 7;   // {0,128,256,384}
    const int i0  = (lid >> 4) << 6;
    const int lane = tid & 63;
    const int wid  = tid >> 6;
    const int lr = lane & 15, cb = lane >> 4;

    for (int e = tid; e < 512; e += 256) {
        int row = e >> 3, ch = e & 7;
        *(int4*)&qps[swz8(row, ch)] =
            *(const int4*)&qb[((size_t)n*HW_ + i0 + row)*CR_ + ch*8];
    }
    const int krow = tid >> 3, kch = tid & 7;
    const bf16s* kbase = kb + (size_t)n*HW_*CR_ + kch*8;
    int4 kreg0 = *(const int4*)(kbase + (size_t)krow*CR_);
    int4 kreg1 = *(const int4*)(kbase + (size_t)(krow + 32)*CR_);
    __syncthreads();
    bf16x8 bq[2];                                // loop-invariant Q fragments
#pragma unroll
    for (int kk = 0; kk < 2; ++kk)
        bq[kk] = *(const bf16x8*)&qps[swz8(wid*16 + lr, kk*4 + cb)];

    // merge the two rowstats partials (exact online-softmax combine)
    const size_t sidx = (size_t)n*HW_ + i0 + wid*16 + lr;
    const float m0 = rowm[sidx], m1 = rowm[sidx + (size_t)N_*HW_];
    const float l0 = rowl[sidx], l1 = rowl[sidx + (size_t)N_*HW_];
    const float mreg = fmaxf(m0, m1);
    const float rinv = 1.f / (l0*__expf(m0 - mreg) + l1*__expf(m1 - mreg));
    const float al = alpha[0];

    f32x4 acc[2][4];                             // [fc2][fi]
#pragma unroll
    for (int i = 0; i < 2; ++i)
#pragma unroll
        for (int j = 0; j < 4; ++j) acc[i][j] = (f32x4){0.f,0.f,0.f,0.f};

    const bf16s* vbase = vb + ((size_t)(n*C_ + cc0 + wid*32))*HW_;

    for (int jt = 0; jt < 64; ++jt) {
        *(int4*)&ks[swz8(krow, kch)] = kreg0;
        *(int4*)&ks[swz8(krow + 32, kch)] = kreg1;
        if (jt < 63) {                           // prefetch next tile (T14)
            kreg0 = *(const int4*)(kbase + (size_t)((jt+1)*64 + krow)*CR_);
            kreg1 = *(const int4*)(kbase + (size_t)((jt+1)*64 + krow + 32)*CR_);
        }
        __syncthreads();                         // B: ks ready, prev PV done
#pragma unroll
        for (int fj = 0; fj < 4; ++fj) {
            f32x4 s = (f32x4){0.f,0.f,0.f,0.f};
#pragma unroll
            for (int kk = 0; kk < 2; ++kk) {
                bf16x8 ak = *(const bf16x8*)&ks[swz8(fj*16 + lr, kk*4 + cb)];
                s = __builtin_amdgcn_mfma_f32_16x16x32_bf16(ak, bq[kk], s, 0, 0, 0);
            }
            unsigned short b[4];
#pragma unroll
            for (int r = 0; r < 4; ++r)
                b[r] = bfb(__expf(s[r] - mreg) * rinv);
            uint2 u;
            u.x = (unsigned)b[0] | ((unsigned)b[1] << 16);
            u.y = (unsigned)b[2] | ((unsigned)b[3] << 16);
            *(uint2*)&qps[swz8(wid*16 + lr, fj*2 + (cb >> 1)) + (cb & 1)*4] = u;
        }
        __syncthreads();                         // C: ps ready
        const bf16s* vj = vbase + jt*64;
#pragma unroll
        for (int kk2 = 0; kk2 < 2; ++kk2) {
            bf16x8 vf[2], pa[4];
#pragma unroll
            for (int fc2 = 0; fc2 < 2; ++fc2)
                vf[fc2] = *(const bf16x8*)(vj + (size_t)(fc2*16 + lr)*HW_
                                              + kk2*32 + cb*8);
#pragma unroll
            for (int fi = 0; fi < 4; ++fi)
                pa[fi] = *(const bf16x8*)&qps[swz8(fi*16 + lr, kk2*4 + cb)];
#pragma unroll
            for (int fc2 = 0; fc2 < 2; ++fc2)
#pragma unroll
                for (int fi = 0; fi < 4; ++fi)
                    acc[fc2][fi] = __builtin_amdgcn_mfma_f32_16x16x32_bf16(
                        vf[fc2], pa[fi], acc[fc2][fi], 0, 0, 0);
        }
    }
    // epilogue: residual add + bf16, direct uint2 stores
#pragma unroll
    for (int fc2 = 0; fc2 < 2; ++fc2) {
        const int ccl = wid*32 + fc2*16 + cb*4;
#pragma unroll
        for (int fi = 0; fi < 4; ++fi) {
            const int p = i0 + fi*16 + lr;
            const float* fp = &feat[((size_t)(n*C_ + cc0 + ccl))*HW_ + p];
            float v0 = fmaf(al, acc[fc2][fi][0], fp[0]);
            float v1 = fmaf(al, acc[fc2][fi][1], fp[(size_t)HW_]);
            float v2 = fmaf(al, acc[fc2][fi][2], fp[(size_t)2*HW_]);
            float v3 = fmaf(al, acc[fc2][fi][3], fp[(size_t)3*HW_]);
            uint2 u;
            u.x = (unsigned)bfb(v0) | ((unsigned)bfb(v1) << 16);
            u.y = (unsigned)bfb(v2) | ((unsigned)bfb(v3) << 16);
            *(uint2*)&featT[((size_t)n*HW_ + p)*C_ + cc0 + ccl] = u;
        }
    }
}

// ---------------------------------------------------------------------------
__global__ __launch_bounds__(64) void k_cmlp(
    const float* __restrict__ s0, const float* __restrict__ Wc1,
    const float* __restrict__ bc1, const float* __restrict__ Wc2,
    const float* __restrict__ bc2, float* __restrict__ s2)
{
    const int n = blockIdx.x, tid = threadIdx.x;
    __shared__ float s1s[64];
    float a = 0.f;
    for (int c = 0; c < C_; ++c)
        a = fmaf(Wc1[(size_t)tid*C_ + c], s0[n*C_ + c] * (1.f/HW_), a);
    a += bc1[tid];
    a = a > 0.f ? a : 0.2f*a;
    s1s[tid] = a;
    __syncthreads();
    for (int c = tid; c < C_; c += 64) {
        float b = 0.f;
        for (int i = 0; i < CR_; ++i) b = fmaf(Wc2[(size_t)c*CR_ + i], s1s[i], b);
        b += bc2[c];
        s2[n*C_ + c] = 1.f / (1.f + __expf(-b));
    }
}

__global__ __launch_bounds__(256) void k_up(
    const float* __restrict__ pl, const float* __restrict__ cl,
    float* __restrict__ out)
{
    int idx = blockIdx.x * 256 + threadIdx.x;
    int ox = idx & 127; int rest = idx >> 7;
    int oy = rest & 127; rest >>= 7;
    int o  = rest & 63;  int n = rest >> 6;
    float fy = oy*0.5f - 0.25f;
    float fx = ox*0.5f - 0.25f;
    int y0 = (int)floorf(fy); float wy = fy - y0;
    int x0 = (int)floorf(fx); float wx = fx - x0;
    int y0c = y0 < 0 ? 0 : y0;      int y1c = y0+1 > 63 ? 63 : y0+1;
    int x0c = x0 < 0 ? 0 : x0;      int x1c = x0+1 > 63 ? 63 : x0+1;
    const float* a = pl + ((size_t)(n*NC_ + o))*HW_;
    const float* b = cl + ((size_t)(n*NC_ + o))*HW_;
    float v00 = a[y0c*64+x0c] + b[y0c*64+x0c];
    float v01 = a[y0c*64+x1c] + b[y0c*64+x1c];
    float v10 = a[y1c*64+x0c] + b[y1c*64+x0c];
    float v11 = a[y1c*64+x1c] + b[y1c*64+x1c];
    out[idx] = (1.f-wy)*((1.f-wx)*v00 + wx*v01) + wy*((1.f-wx)*v10 + wx*v11);
}

// ---------------------------------------------------------------------------
extern "C" void kernel_launch(void* const* d_in, const int* in_sizes, int n_in,
                              void* d_out, int out_size, void* d_ws, size_t ws_size,
                              hipStream_t stream)
{
    const float* x         = (const float*)d_in[0];
    const float* W_pam_in  = (const float*)d_in[1];
    const float* pam_g     = (const float*)d_in[2];
    const float* pam_b     = (const float*)d_in[3];
    const float* pam_m     = (const float*)d_in[4];
    const float* pam_v     = (const float*)d_in[5];
    const float* Wq        = (const float*)d_in[6];
    const float* bq        = (const float*)d_in[7];
    const float* Wk        = (const float*)d_in[8];
    const float* bk        = (const float*)d_in[9];
    const float* Wv        = (const float*)d_in[10];
    const float* bv        = (const float*)d_in[11];
    const float* alpha     = (const float*)d_in[12];
    const float* W_pam_out = (const float*)d_in[13];
    const float* b_pam_out = (const float*)d_in[14];
    const float* W_cam_in  = (const float*)d_in[15];
    const float* cam_g     = (const float*)d_in[16];
    const float* cam_b     = (const float*)d_in[17];
    const float* cam_m     = (const float*)d_in[18];
    const float* cam_v     = (const float*)d_in[19];
    const float* Wc1       = (const float*)d_in[20];
    const float* bc1       = (const float*)d_in[21];
    const float* Wc2       = (const float*)d_in[22];
    const float* bc2       = (const float*)d_in[23];
    const float* W_cam_out = (const float*)d_in[24];
    const float* b_cam_out = (const float*)d_in[25];

    float* feat    = (float*)d_ws;             // [4][512][4096] fp32
    float* pam_low = feat    + 8388608;        // [4][64][4096]
    float* rowm    = pam_low + 1048576;        // [2][4][4096] partials
    float* rowl    = rowm    + 32768;          // [2][4][4096]
    float* s0      = rowl    + 32768;          // [4][512]
    float* s2      = s0      + 2048;
    bf16s* xbT     = (bf16s*)(s2 + 2048);      // [4][4096][512] bf16
    bf16s* featTb  = xbT + 8388608;            // [4][4096][512]
    bf16s* vb      = featTb + 8388608;         // [4][512][4096]
    bf16s* qb      = vb + 8388608;             // [4][4096][64]
    bf16s* kb      = qb + 1048576;
    bf16s* wbp     = kb + 1048576;             // [512][9][512] (shared pam/cam)
    bf16s* Wqb     = wbp + 2359296;            // [64][512]
    bf16s* Wkb     = Wqb + 32768;
    bf16s* Wvb     = Wkb + 32768;              // [512][512]
    bf16s* Wpob    = Wvb + 262144;             // [64][512]
    bf16s* Wcob    = Wpob + 32768;             // [64][512]
    float* cam_low = (float*)qb;               // aliases qb+kb (dead after k_pv)

    dim3 b256(256);
    k_xpose<<<dim3(64,8,4), b256, 0, stream>>>(x, xbT);
    k_wcast<<<dim3(128), b256, 0, stream>>>(Wq, Wqb, 32768);
    k_wcast<<<dim3(128), b256, 0, stream>>>(Wk, Wkb, 32768);
    k_wcast<<<dim3(1024), b256, 0, stream>>>(Wv, Wvb, 262144);
    k_wcast<<<dim3(128), b256, 0, stream>>>(W_pam_out, Wpob, 32768);
    k_wcast<<<dim3(128), b256, 0, stream>>>(W_cam_out, Wcob, 32768);
    hipMemsetAsync(s0, 0, 2048*sizeof(float), stream);   // channel-sum accum
    // PAM branch
    k_wprep<<<dim3(9216), b256, 0, stream>>>(W_pam_in, wbp);
    k_conv3x3_mfma<<<dim3(32,4,4), b256, 0, stream>>>(
        xbT, wbp, pam_g, pam_b, pam_m, pam_v, feat, featTb, nullptr, 0);
    k_gemm<<<dim3(16,1,4), b256, 0, stream>>>(Wqb, featTb, bq, nullptr, qb, 64, 1);
    k_gemm<<<dim3(16,1,4), b256, 0, stream>>>(Wkb, featTb, bk, nullptr, kb, 64, 1);
    k_gemm<<<dim3(16,8,4), b256, 0, stream>>>(Wvb, featTb, bv, nullptr, vb, 512, 2);
    k_rowstats_mfma<<<dim3(64,4,2), b256, 0, stream>>>(qb, kb, rowm, rowl);
    k_pv_mfma<<<dim3(64,4,4), b256, 0, stream>>>(
        qb, kb, vb, rowm, rowl, alpha, feat, featTb);
    k_gemm<<<dim3(16,1,4), b256, 0, stream>>>(
        Wpob, featTb, b_pam_out, nullptr, pam_low, 64, 0);
    // CAM branch (reuses featTb + wbp; no fp32 feat write, sums fused)
    k_wprep<<<dim3(9216), b256, 0, stream>>>(W_cam_in, wbp);
    k_conv3x3_mfma<<<dim3(32,4,4), b256, 0, stream>>>(
        xbT, wbp, cam_g, cam_b, cam_m, cam_v, feat, featTb, s0, 1);
    k_cmlp<<<dim3(4), dim3(64), 0, stream>>>(s0, Wc1, bc1, Wc2, bc2, s2);
    k_gemm<<<dim3(16,1,4), b256, 0, stream>>>(
        Wcob, featTb, b_cam_out, s2, cam_low, 64, 0);
    // upsample + add
    k_up<<<dim3(16384), b256, 0, stream>>>(pam_low, cam_low, (float*)d_out);
}

// Round 3
// 482.742 us; speedup vs baseline: 1.5842x; 1.5842x over previous
//
#include <hip/hip_runtime.h>
#include <hip/hip_bf16.h>
#include <math.h>

#define N_  4
#define C_  512
#define H_  64
#define W_  64
#define HW_ 4096
#define CR_ 64
#define NC_ 64
#define EPSV 1e-5f

typedef __attribute__((ext_vector_type(8))) __bf16 bf16x8;
typedef __attribute__((ext_vector_type(4))) float f32x4;
typedef __hip_bfloat16 bf16s;

__device__ __forceinline__ unsigned short bfb(float f) {
    union { bf16s h; unsigned short u; } cv;
    cv.h = __float2bfloat16(f);
    return cv.u;
}

// XOR-swizzled element offset for a [64][64] bf16 LDS tile (128 B rows,
// 8 chunks of 16 B). chunk' = chunk ^ (row&7) -> conflict-free b128 access.
__device__ __forceinline__ int swz8(int row, int ch) {
    return row * 64 + ((ch ^ (row & 7)) << 3);
}

// ---------------------------------------------------------------------------
// x [n][c][hw] fp32 -> xbT [n][hw][c] bf16
// ---------------------------------------------------------------------------
__global__ __launch_bounds__(256) void k_xpose(
    const float* __restrict__ x, bf16s* __restrict__ xbT)
{
    __shared__ float xs[64][65];
    const int tid = threadIdx.x;
    const int n = blockIdx.z, c0 = blockIdx.y * 64, p0 = blockIdx.x * 64;
    for (int e = tid; e < 4096; e += 256) {
        int ci = e >> 6, pi = e & 63;
        xs[ci][pi] = x[((size_t)(n*C_ + c0 + ci))*HW_ + p0 + pi];
    }
    __syncthreads();
    for (int e = tid; e < 4096; e += 256) {
        int pi = e >> 6, ci = e & 63;
        xbT[((size_t)n*HW_ + p0 + pi)*C_ + c0 + ci] = __float2bfloat16(xs[ci][pi]);
    }
}

// w [o][c][3][3] fp32 -> wb [o][tap][c] bf16
__global__ __launch_bounds__(256) void k_wprep(
    const float* __restrict__ w, bf16s* __restrict__ wb)
{
    int e = blockIdx.x * 256 + threadIdx.x;           // < 512*9*512
    int c = e & 511; int r = e >> 9;
    int tap = r % 9; int o = r / 9;
    wb[e] = __float2bfloat16(w[((size_t)o*C_ + c)*9 + tap]);
}

// flat fp32 -> bf16 cast
__global__ __launch_bounds__(256) void k_wcast(
    const float* __restrict__ in, bf16s* __restrict__ out, int nElem)
{
    int e = blockIdx.x * 256 + threadIdx.x;
    if (e < nElem) out[e] = __float2bfloat16(in[e]);
}

// ---------------------------------------------------------------------------
// conv3x3 + BN + LReLU implicit-GEMM MFMA.
// mode 0 (PAM): writes feat fp32 [c][p] AND featT bf16 [p][c]
// mode 1 (CAM): writes featT only + atomicAdd per-channel activation sums.
// T14 prefetch via NAMED registers (R2's array version spilled to scratch:
// VGPR 92, WRITE_SIZE 4x). __launch_bounds__(256,2): grid-capped at
// 2 blk/CU anyway -> allocator free to 256 VGPRs.
// ---------------------------------------------------------------------------
__global__ __launch_bounds__(256, 2) void k_conv3x3_mfma(
    const bf16s* __restrict__ xbT, const bf16s* __restrict__ wb,
    const float* __restrict__ gamma, const float* __restrict__ beta,
    const float* __restrict__ mean, const float* __restrict__ var,
    float* __restrict__ out, bf16s* __restrict__ featT,
    float* __restrict__ csum, int mode)
{
    __shared__ bf16s aL[3][128][40];
    __shared__ bf16s bL[132][40];            // [ry*66+xi][ch]
    const int tid = threadIdx.x;
    const int n  = blockIdx.z;
    const int o0 = blockIdx.y * 128;
    const int pt = blockIdx.x;
    const int y0 = pt * 2;
    const int lane = tid & 63;
    const int wid  = tid >> 6;
    const int wr = wid >> 1, wc = wid & 1;
    const int lr = lane & 15, cb = lane >> 4;

    // per-thread staging coordinates (constant across iterations)
    const int ao  = tid >> 2;                // A row within half
    const int ac  = (tid & 3) * 8;           // chunk offset (elems)
    const int t0  = tid >> 2;                // B token k=0 (ry=0, xi=t0)
    const int t1  = t0 + 64;                 // B token k=1
    const int t2  = t0 + 128;                // B token k=2 (valid if tid<16)
    const int ry1 = t1 >= 66 ? 1 : 0;
    const int xi1 = t1 - (ry1 ? 66 : 0);

    f32x4 acc[4][4];
#pragma unroll
    for (int i = 0; i < 4; ++i)
#pragma unroll
        for (int j = 0; j < 4; ++j) acc[i][j] = (f32x4){0.f,0.f,0.f,0.f};

    int4 pA0, pA1, pA2, pA3, pA4, pA5, pB0, pB1, pB2;

#define CONV_AADDR(DXI, OHALF, C0, DYI) \
    (const int4*)(wb + ((size_t)(o0 + (OHALF) + ao)*9 + (DYI)*3 + (DXI))*C_ + (C0) + ac)

#define CONV_BLOAD(DST, RY, XI, C0, DYI, VALID)                               \
    {                                                                         \
        int row_ = y0 + (DYI) - 1 + (RY);                                     \
        int xc_  = (XI) - 1;                                                  \
        int4 v_ = {0,0,0,0};                                                  \
        if ((VALID) && row_ >= 0 && row_ < H_ && xc_ >= 0 && xc_ < W_)        \
            v_ = *(const int4*)(xbT +                                         \
                ((size_t)n*HW_ + row_*W_ + xc_)*C_ + (C0) + ac);              \
        DST = v_;                                                             \
    }

#define CONV_ISSUE(C0, DYI)                                                   \
    {                                                                         \
        pA0 = *CONV_AADDR(0,  0, C0, DYI);                                    \
        pA1 = *CONV_AADDR(0, 64, C0, DYI);                                    \
        pA2 = *CONV_AADDR(1,  0, C0, DYI);                                    \
        pA3 = *CONV_AADDR(1, 64, C0, DYI);                                    \
        pA4 = *CONV_AADDR(2,  0, C0, DYI);                                    \
        pA5 = *CONV_AADDR(2, 64, C0, DYI);                                    \
        CONV_BLOAD(pB0, 0, t0, C0, DYI, 1)                                    \
        CONV_BLOAD(pB1, ry1, xi1, C0, DYI, 1)                                 \
        CONV_BLOAD(pB2, 1, t2 - 66, C0, DYI, tid < 16)                        \
    }

    CONV_ISSUE(0, 0)
    int c0 = 0, dyi = 0;
    for (int it = 0; it < 48; ++it) {
        // commit prefetched regs -> LDS (compiler inserts the vmcnt wait)
        *(int4*)&aL[0][ao][ac]      = pA0;
        *(int4*)&aL[0][64 + ao][ac] = pA1;
        *(int4*)&aL[1][ao][ac]      = pA2;
        *(int4*)&aL[1][64 + ao][ac] = pA3;
        *(int4*)&aL[2][ao][ac]      = pA4;
        *(int4*)&aL[2][64 + ao][ac] = pA5;
        *(int4*)&bL[t0][ac] = pB0;
        *(int4*)&bL[t1][ac] = pB1;
        if (tid < 16) *(int4*)&bL[t2][ac] = pB2;
        __syncthreads();                     // tiles(it) visible
        int nd = dyi + 1, nc = c0;
        if (nd == 3) { nd = 0; nc += 32; }
        if (it < 47) CONV_ISSUE(nc, nd)      // overlap with MFMA below
#pragma unroll
        for (int dxi = 0; dxi < 3; ++dxi) {
            bf16x8 af[4], bfv[4];
#pragma unroll
            for (int fm = 0; fm < 4; ++fm)
                af[fm] = *(const bf16x8*)&aL[dxi][wr*64 + fm*16 + lr][cb*8];
#pragma unroll
            for (int fn = 0; fn < 4; ++fn) {
                int pg = wc*64 + fn*16 + lr;
                int ry = pg >> 6, xc = pg & 63;
                bfv[fn] = *(const bf16x8*)&bL[ry*66 + xc + dxi][cb*8];
            }
#pragma unroll
            for (int fm = 0; fm < 4; ++fm)
#pragma unroll
                for (int fn = 0; fn < 4; ++fn)
                    acc[fm][fn] = __builtin_amdgcn_mfma_f32_16x16x32_bf16(
                        af[fm], bfv[fn], acc[fm][fn], 0, 0, 0);
        }
        __syncthreads();                     // readers(it) done
        c0 = nc; dyi = nd;
    }
#undef CONV_ISSUE
#undef CONV_BLOAD
#undef CONV_AADDR
#pragma unroll
    for (int fm = 0; fm < 4; ++fm) {
        float sc[4], sh[4];
        const int obase = o0 + wr*64 + fm*16 + cb*4;
#pragma unroll
        for (int r = 0; r < 4; ++r) {
            int o = obase + r;
            sc[r] = gamma[o] * rsqrtf(var[o] + EPSV);
            sh[r] = beta[o] - mean[o]*sc[r];
        }
        float ps[4] = {0.f, 0.f, 0.f, 0.f};
#pragma unroll
        for (int fn = 0; fn < 4; ++fn) {
            int pg = wc*64 + fn*16 + lr;
            int p  = pt*128 + pg;
            float vv[4];
#pragma unroll
            for (int r = 0; r < 4; ++r) {
                float t = fmaf(acc[fm][fn][r], sc[r], sh[r]);
                vv[r] = t > 0.f ? t : 0.2f*t;
                if (mode == 0)
                    out[((size_t)(n*C_ + obase + r))*HW_ + p] = vv[r];
                else
                    ps[r] += vv[r];
            }
            uint2 u;
            u.x = (unsigned)bfb(vv[0]) | ((unsigned)bfb(vv[1]) << 16);
            u.y = (unsigned)bfb(vv[2]) | ((unsigned)bfb(vv[3]) << 16);
            *(uint2*)&featT[((size_t)n*HW_ + p)*C_ + obase] = u;
        }
        if (mode != 0) {
            // per-channel activation sums; 16 p-lanes share channels
#pragma unroll
            for (int r = 0; r < 4; ++r) {
                float s = ps[r];
                s += __shfl_xor(s, 1);
                s += __shfl_xor(s, 2);
                s += __shfl_xor(s, 4);
                s += __shfl_xor(s, 8);
                if (lr == 0) atomicAdd(&csum[n*C_ + obase + r], s);
            }
        }
    }
}

// ---------------------------------------------------------------------------
// bf16 MFMA GEMM: out[o][p] = (A[o][:] * scale?) . Bt[p][:] + bias[o]
// mode 0: fp32 out [n][O][p]; mode 1: bf16 out [n][p][O]; mode 2: bf16 [n][O][p]
// grid (HW/256, O/64, n), block 256. Named-register T14 prefetch.
// ---------------------------------------------------------------------------
__global__ __launch_bounds__(256, 2) void k_gemm(
    const bf16s* __restrict__ A, const bf16s* __restrict__ Bt,
    const float* __restrict__ bias, const float* __restrict__ scale,
    void* __restrict__ outp, int O, int mode)
{
    __shared__ bf16s aL[64][40];
    __shared__ bf16s bL[256][40];
    const int tid = threadIdx.x;
    const int n  = blockIdx.z;
    const int p0 = blockIdx.x * 256;
    const int o0 = blockIdx.y * 64;
    const int lane = tid & 63;
    const int wid  = tid >> 6;
    const int lr = lane & 15, cb = lane >> 4;
    const int arow = tid >> 2, ach = (tid & 3) * 8;

    f32x4 acc[4][4];
#pragma unroll
    for (int i = 0; i < 4; ++i)
#pragma unroll
        for (int j = 0; j < 4; ++j) acc[i][j] = (f32x4){0.f,0.f,0.f,0.f};

    int4 pA, pB0, pB1, pB2, pB3;
    float4 pS0, pS1;

#define GEMM_ISSUE(C0)                                                        \
    {                                                                         \
        pA = *(const int4*)&A[(size_t)(o0 + arow)*C_ + (C0) + ach];           \
        if (scale) {                                                          \
            pS0 = *(const float4*)&scale[(size_t)n*C_ + (C0) + ach];          \
            pS1 = *(const float4*)&scale[(size_t)n*C_ + (C0) + ach + 4];      \
        }                                                                     \
        pB0 = *(const int4*)&Bt[((size_t)n*HW_ + p0 + arow      )*C_ + (C0) + ach]; \
        pB1 = *(const int4*)&Bt[((size_t)n*HW_ + p0 + arow +  64)*C_ + (C0) + ach]; \
        pB2 = *(const int4*)&Bt[((size_t)n*HW_ + p0 + arow + 128)*C_ + (C0) + ach]; \
        pB3 = *(const int4*)&Bt[((size_t)n*HW_ + p0 + arow + 192)*C_ + (C0) + ach]; \
    }

    GEMM_ISSUE(0)
    for (int c0 = 0; c0 < C_; c0 += 32) {
        if (scale) {
            const bf16s* sp = (const bf16s*)&pA;
            bf16s tmp[8];
            tmp[0] = __float2bfloat16(__bfloat162float(sp[0]) * pS0.x);
            tmp[1] = __float2bfloat16(__bfloat162float(sp[1]) * pS0.y);
            tmp[2] = __float2bfloat16(__bfloat162float(sp[2]) * pS0.z);
            tmp[3] = __float2bfloat16(__bfloat162float(sp[3]) * pS0.w);
            tmp[4] = __float2bfloat16(__bfloat162float(sp[4]) * pS1.x);
            tmp[5] = __float2bfloat16(__bfloat162float(sp[5]) * pS1.y);
            tmp[6] = __float2bfloat16(__bfloat162float(sp[6]) * pS1.z);
            tmp[7] = __float2bfloat16(__bfloat162float(sp[7]) * pS1.w);
            *(int4*)&aL[arow][ach] = *(int4*)tmp;
        } else {
            *(int4*)&aL[arow][ach] = pA;
        }
        *(int4*)&bL[arow      ][ach] = pB0;
        *(int4*)&bL[arow +  64][ach] = pB1;
        *(int4*)&bL[arow + 128][ach] = pB2;
        *(int4*)&bL[arow + 192][ach] = pB3;
        __syncthreads();
        if (c0 + 32 < C_) GEMM_ISSUE(c0 + 32)    // overlap with MFMA below
        bf16x8 af[4], bfv[4];
#pragma unroll
        for (int fo = 0; fo < 4; ++fo)
            af[fo] = *(const bf16x8*)&aL[fo*16 + lr][cb*8];
#pragma unroll
        for (int fp = 0; fp < 4; ++fp)
            bfv[fp] = *(const bf16x8*)&bL[wid*64 + fp*16 + lr][cb*8];
#pragma unroll
        for (int fo = 0; fo < 4; ++fo)
#pragma unroll
            for (int fp = 0; fp < 4; ++fp)
                acc[fo][fp] = __builtin_amdgcn_mfma_f32_16x16x32_bf16(
                    af[fo], bfv[fp], acc[fo][fp], 0, 0, 0);
        __syncthreads();
    }
#undef GEMM_ISSUE
#pragma unroll
    for (int fo = 0; fo < 4; ++fo) {
        const int obase = o0 + fo*16 + cb*4;
        float bv[4];
#pragma unroll
        for (int r = 0; r < 4; ++r) bv[r] = bias[obase + r];
#pragma unroll
        for (int fp = 0; fp < 4; ++fp) {
            int p = p0 + wid*64 + fp*16 + lr;
            float v[4];
#pragma unroll
            for (int r = 0; r < 4; ++r) v[r] = acc[fo][fp][r] + bv[r];
            if (mode == 1) {
                uint2 u;
                u.x = (unsigned)bfb(v[0]) | ((unsigned)bfb(v[1]) << 16);
                u.y = (unsigned)bfb(v[2]) | ((unsigned)bfb(v[3]) << 16);
                *(uint2*)&((bf16s*)outp)[((size_t)n*HW_ + p)*O + (obase - o0)] = u;
            } else if (mode == 2) {
#pragma unroll
                for (int r = 0; r < 4; ++r)
                    ((bf16s*)outp)[((size_t)(n*O + obase + r))*HW_ + p] =
                        __float2bfloat16(v[r]);
            } else {
#pragma unroll
                for (int r = 0; r < 4; ++r)
                    ((float*)outp)[((size_t)(n*O + obase + r))*HW_ + p] = v[r];
            }
        }
    }
}

// ---------------------------------------------------------------------------
// pass A: partial rowm/rowl via S^T = mfma(K, Q), j-split x2 across grid.z.
// ---------------------------------------------------------------------------
__global__ __launch_bounds__(256) void k_rowstats_mfma(
    const bf16s* __restrict__ qb, const bf16s* __restrict__ kb,
    float* __restrict__ rowm, float* __restrict__ rowl)
{
    __shared__ bf16s qs[4096];
    __shared__ bf16s ks[4096];
    const int tid = threadIdx.x;
    const int lid = blockIdx.x + (blockIdx.y << 6) + (blockIdx.z << 8);
    const int n  = lid & 3;
    const int jz = (lid >> 2) & 1;
    const int i0 = (lid >> 3) << 6;
    const int lane = tid & 63;
    const int wid  = tid >> 6;
    const int lr = lane & 15, cb = lane >> 4;

    for (int e = tid; e < 512; e += 256) {
        int row = e >> 3, ch = e & 7;
        *(int4*)&qs[swz8(row, ch)] =
            *(const int4*)&qb[((size_t)n*HW_ + i0 + row)*CR_ + ch*8];
    }
    const int krow = tid >> 3, kch = tid & 7;
    const bf16s* kbase = kb + (size_t)n*HW_*CR_ + (size_t)jz*2048*CR_ + kch*8;
    int4 kreg0 = *(const int4*)(kbase + (size_t)krow*CR_);
    int4 kreg1 = *(const int4*)(kbase + (size_t)(krow + 32)*CR_);
    __syncthreads();
    bf16x8 bq[2];
#pragma unroll
    for (int kk = 0; kk < 2; ++kk)
        bq[kk] = *(const bf16x8*)&qs[swz8(wid*16 + lr, kk*4 + cb)];

    float m_t = -INFINITY, l_t = 0.f;
    for (int t = 0; t < 32; ++t) {
        __syncthreads();                       // S^T(t-1) readers done
        *(int4*)&ks[swz8(krow, kch)] = kreg0;
        *(int4*)&ks[swz8(krow + 32, kch)] = kreg1;
        if (t < 31) {                          // prefetch next K tile (T14)
            kreg0 = *(const int4*)(kbase + (size_t)((t+1)*64 + krow)*CR_);
            kreg1 = *(const int4*)(kbase + (size_t)((t+1)*64 + krow + 32)*CR_);
        }
        __syncthreads();
        f32x4 sv[4];
#pragma unroll
        for (int fj = 0; fj < 4; ++fj) {
            f32x4 s = (f32x4){0.f,0.f,0.f,0.f};
#pragma unroll
            for (int kk = 0; kk < 2; ++kk) {
                bf16x8 ak = *(const bf16x8*)&ks[swz8(fj*16 + lr, kk*4 + cb)];
                s = __builtin_amdgcn_mfma_f32_16x16x32_bf16(ak, bq[kk], s, 0, 0, 0);
            }
            sv[fj] = s;
        }
        float mx = m_t;
#pragma unroll
        for (int fj = 0; fj < 4; ++fj)
#pragma unroll
            for (int r = 0; r < 4; ++r) mx = fmaxf(mx, sv[fj][r]);
        float sum = 0.f;
#pragma unroll
        for (int fj = 0; fj < 4; ++fj)
#pragma unroll
            for (int r = 0; r < 4; ++r) sum += __expf(sv[fj][r] - mx);
        l_t = l_t * __expf(m_t - mx) + sum;
        m_t = mx;
    }
#pragma unroll
    for (int mask = 16; mask <= 32; mask <<= 1) {
        float mo = __shfl_xor(m_t, mask);
        float lo = __shfl_xor(l_t, mask);
        float m2 = fmaxf(m_t, mo);
        l_t = l_t * __expf(m_t - m2) + lo * __expf(mo - m2);
        m_t = m2;
    }
    if (cb == 0) {
        rowm[((size_t)jz*N_ + n)*HW_ + i0 + wid*16 + lr] = m_t;
        rowl[((size_t)jz*N_ + n)*HW_ + i0 + wid*16 + lr] = l_t;
    }
}

// ---------------------------------------------------------------------------
// pass B: block = 64 i x 128 c. Per jt: S^T MFMA -> exp -> P bf16 LDS ->
// PV MFMA (V direct from global). Swizzled 16 KB LDS, Q hoisted, K
// reg-prefetched, 2 barriers/iter. XCD-pinned n.
// ---------------------------------------------------------------------------
__global__ __launch_bounds__(256, 4) void k_pv_mfma(
    const bf16s* __restrict__ qb, const bf16s* __restrict__ kb,
    const bf16s* __restrict__ vb, const float* __restrict__ rowm,
    const float* __restrict__ rowl, const float* __restrict__ alpha,
    const float* __restrict__ feat, bf16s* __restrict__ featT)
{
    __shared__ bf16s ks[4096];
    __shared__ bf16s qps[4096];                  // Q staging, then P
    const int tid = threadIdx.x;
    const int lid = blockIdx.x + (blockIdx.y << 6) + (blockIdx.z << 8);
    const int k8  = lid & 7;
    const int n   = k8 >> 1;
    const int cc0 = (((lid >> 3) & 1) * 2 + (k8 & 1)) << 7;   // {0,128,256,384}
    const int i0  = (lid >> 4) << 6;
    const int lane = tid & 63;
    const int wid  = tid >> 6;
    const int lr = lane & 15, cb = lane >> 4;

    for (int e = tid; e < 512; e += 256) {
        int row = e >> 3, ch = e & 7;
        *(int4*)&qps[swz8(row, ch)] =
            *(const int4*)&qb[((size_t)n*HW_ + i0 + row)*CR_ + ch*8];
    }
    const int krow = tid >> 3, kch = tid & 7;
    const bf16s* kbase = kb + (size_t)n*HW_*CR_ + kch*8;
    int4 kreg0 = *(const int4*)(kbase + (size_t)krow*CR_);
    int4 kreg1 = *(const int4*)(kbase + (size_t)(krow + 32)*CR_);
    __syncthreads();
    bf16x8 bq[2];                                // loop-invariant Q fragments
#pragma unroll
    for (int kk = 0; kk < 2; ++kk)
        bq[kk] = *(const bf16x8*)&qps[swz8(wid*16 + lr, kk*4 + cb)];

    // merge the two rowstats partials (exact online-softmax combine)
    const size_t sidx = (size_t)n*HW_ + i0 + wid*16 + lr;
    const float m0 = rowm[sidx], m1 = rowm[sidx + (size_t)N_*HW_];
    const float l0 = rowl[sidx], l1 = rowl[sidx + (size_t)N_*HW_];
    const float mreg = fmaxf(m0, m1);
    const float rinv = 1.f / (l0*__expf(m0 - mreg) + l1*__expf(m1 - mreg));
    const float al = alpha[0];

    f32x4 acc[2][4];                             // [fc2][fi]
#pragma unroll
    for (int i = 0; i < 2; ++i)
#pragma unroll
        for (int j = 0; j < 4; ++j) acc[i][j] = (f32x4){0.f,0.f,0.f,0.f};

    const bf16s* vbase = vb + ((size_t)(n*C_ + cc0 + wid*32))*HW_;

    for (int jt = 0; jt < 64; ++jt) {
        *(int4*)&ks[swz8(krow, kch)] = kreg0;
        *(int4*)&ks[swz8(krow + 32, kch)] = kreg1;
        if (jt < 63) {                           // prefetch next tile (T14)
            kreg0 = *(const int4*)(kbase + (size_t)((jt+1)*64 + krow)*CR_);
            kreg1 = *(const int4*)(kbase + (size_t)((jt+1)*64 + krow + 32)*CR_);
        }
        __syncthreads();                         // B: ks ready, prev PV done
#pragma unroll
        for (int fj = 0; fj < 4; ++fj) {
            f32x4 s = (f32x4){0.f,0.f,0.f,0.f};
#pragma unroll
            for (int kk = 0; kk < 2; ++kk) {
                bf16x8 ak = *(const bf16x8*)&ks[swz8(fj*16 + lr, kk*4 + cb)];
                s = __builtin_amdgcn_mfma_f32_16x16x32_bf16(ak, bq[kk], s, 0, 0, 0);
            }
            unsigned short b[4];
#pragma unroll
            for (int r = 0; r < 4; ++r)
                b[r] = bfb(__expf(s[r] - mreg) * rinv);
            uint2 u;
            u.x = (unsigned)b[0] | ((unsigned)b[1] << 16);
            u.y = (unsigned)b[2] | ((unsigned)b[3] << 16);
            *(uint2*)&qps[swz8(wid*16 + lr, fj*2 + (cb >> 1)) + (cb & 1)*4] = u;
        }
        __syncthreads();                         // C: ps ready
        const bf16s* vj = vbase + jt*64;
#pragma unroll
        for (int kk2 = 0; kk2 < 2; ++kk2) {
            bf16x8 vf[2], pa[4];
#pragma unroll
            for (int fc2 = 0; fc2 < 2; ++fc2)
                vf[fc2] = *(const bf16x8*)(vj + (size_t)(fc2*16 + lr)*HW_
                                              + kk2*32 + cb*8);
#pragma unroll
            for (int fi = 0; fi < 4; ++fi)
                pa[fi] = *(const bf16x8*)&qps[swz8(fi*16 + lr, kk2*4 + cb)];
#pragma unroll
            for (int fc2 = 0; fc2 < 2; ++fc2)
#pragma unroll
                for (int fi = 0; fi < 4; ++fi)
                    acc[fc2][fi] = __builtin_amdgcn_mfma_f32_16x16x32_bf16(
                        vf[fc2], pa[fi], acc[fc2][fi], 0, 0, 0);
        }
    }
    // epilogue: residual add + bf16, direct uint2 stores
#pragma unroll
    for (int fc2 = 0; fc2 < 2; ++fc2) {
        const int ccl = wid*32 + fc2*16 + cb*4;
#pragma unroll
        for (int fi = 0; fi < 4; ++fi) {
            const int p = i0 + fi*16 + lr;
            const float* fp = &feat[((size_t)(n*C_ + cc0 + ccl))*HW_ + p];
            float v0 = fmaf(al, acc[fc2][fi][0], fp[0]);
            float v1 = fmaf(al, acc[fc2][fi][1], fp[(size_t)HW_]);
            float v2 = fmaf(al, acc[fc2][fi][2], fp[(size_t)2*HW_]);
            float v3 = fmaf(al, acc[fc2][fi][3], fp[(size_t)3*HW_]);
            uint2 u;
            u.x = (unsigned)bfb(v0) | ((unsigned)bfb(v1) << 16);
            u.y = (unsigned)bfb(v2) | ((unsigned)bfb(v3) << 16);
            *(uint2*)&featT[((size_t)n*HW_ + p)*C_ + cc0 + ccl] = u;
        }
    }
}

// ---------------------------------------------------------------------------
__global__ __launch_bounds__(64) void k_cmlp(
    const float* __restrict__ s0, const float* __restrict__ Wc1,
    const float* __restrict__ bc1, const float* __restrict__ Wc2,
    const float* __restrict__ bc2, float* __restrict__ s2)
{
    const int n = blockIdx.x, tid = threadIdx.x;
    __shared__ float s1s[64];
    float a = 0.f;
    for (int c = 0; c < C_; ++c)
        a = fmaf(Wc1[(size_t)tid*C_ + c], s0[n*C_ + c] * (1.f/HW_), a);
    a += bc1[tid];
    a = a > 0.f ? a : 0.2f*a;
    s1s[tid] = a;
    __syncthreads();
    for (int c = tid; c < C_; c += 64) {
        float b = 0.f;
        for (int i = 0; i < CR_; ++i) b = fmaf(Wc2[(size_t)c*CR_ + i], s1s[i], b);
        b += bc2[c];
        s2[n*C_ + c] = 1.f / (1.f + __expf(-b));
    }
}

__global__ __launch_bounds__(256) void k_up(
    const float* __restrict__ pl, const float* __restrict__ cl,
    float* __restrict__ out)
{
    int idx = blockIdx.x * 256 + threadIdx.x;
    int ox = idx & 127; int rest = idx >> 7;
    int oy = rest & 127; rest >>= 7;
    int o  = rest & 63;  int n = rest >> 6;
    float fy = oy*0.5f - 0.25f;
    float fx = ox*0.5f - 0.25f;
    int y0 = (int)floorf(fy); float wy = fy - y0;
    int x0 = (int)floorf(fx); float wx = fx - x0;
    int y0c = y0 < 0 ? 0 : y0;      int y1c = y0+1 > 63 ? 63 : y0+1;
    int x0c = x0 < 0 ? 0 : x0;      int x1c = x0+1 > 63 ? 63 : x0+1;
    const float* a = pl + ((size_t)(n*NC_ + o))*HW_;
    const float* b = cl + ((size_t)(n*NC_ + o))*HW_;
    float v00 = a[y0c*64+x0c] + b[y0c*64+x0c];
    float v01 = a[y0c*64+x1c] + b[y0c*64+x1c];
    float v10 = a[y1c*64+x0c] + b[y1c*64+x0c];
    float v11 = a[y1c*64+x1c] + b[y1c*64+x1c];
    out[idx] = (1.f-wy)*((1.f-wx)*v00 + wx*v01) + wy*((1.f-wx)*v10 + wx*v11);
}

// ---------------------------------------------------------------------------
extern "C" void kernel_launch(void* const* d_in, const int* in_sizes, int n_in,
                              void* d_out, int out_size, void* d_ws, size_t ws_size,
                              hipStream_t stream)
{
    const float* x         = (const float*)d_in[0];
    const float* W_pam_in  = (const float*)d_in[1];
    const float* pam_g     = (const float*)d_in[2];
    const float* pam_b     = (const float*)d_in[3];
    const float* pam_m     = (const float*)d_in[4];
    const float* pam_v     = (const float*)d_in[5];
    const float* Wq        = (const float*)d_in[6];
    const float* bq        = (const float*)d_in[7];
    const float* Wk        = (const float*)d_in[8];
    const float* bk        = (const float*)d_in[9];
    const float* Wv        = (const float*)d_in[10];
    const float* bv        = (const float*)d_in[11];
    const float* alpha     = (const float*)d_in[12];
    const float* W_pam_out = (const float*)d_in[13];
    const float* b_pam_out = (const float*)d_in[14];
    const float* W_cam_in  = (const float*)d_in[15];
    const float* cam_g     = (const float*)d_in[16];
    const float* cam_b     = (const float*)d_in[17];
    const float* cam_m     = (const float*)d_in[18];
    const float* cam_v     = (const float*)d_in[19];
    const float* Wc1       = (const float*)d_in[20];
    const float* bc1       = (const float*)d_in[21];
    const float* Wc2       = (const float*)d_in[22];
    const float* bc2       = (const float*)d_in[23];
    const float* W_cam_out = (const float*)d_in[24];
    const float* b_cam_out = (const float*)d_in[25];

    float* feat    = (float*)d_ws;             // [4][512][4096] fp32
    float* pam_low = feat    + 8388608;        // [4][64][4096]
    float* rowm    = pam_low + 1048576;        // [2][4][4096] partials
    float* rowl    = rowm    + 32768;          // [2][4][4096]
    float* s0      = rowl    + 32768;          // [4][512]
    float* s2      = s0      + 2048;
    bf16s* xbT     = (bf16s*)(s2 + 2048);      // [4][4096][512] bf16
    bf16s* featTb  = xbT + 8388608;            // [4][4096][512]
    bf16s* vb      = featTb + 8388608;         // [4][512][4096]
    bf16s* qb      = vb + 8388608;             // [4][4096][64]
    bf16s* kb      = qb + 1048576;
    bf16s* wbp     = kb + 1048576;             // [512][9][512] (shared pam/cam)
    bf16s* Wqb     = wbp + 2359296;            // [64][512]
    bf16s* Wkb     = Wqb + 32768;
    bf16s* Wvb     = Wkb + 32768;              // [512][512]
    bf16s* Wpob    = Wvb + 262144;             // [64][512]
    bf16s* Wcob    = Wpob + 32768;             // [64][512]
    float* cam_low = (float*)qb;               // aliases qb+kb (dead after k_pv)

    dim3 b256(256);
    k_xpose<<<dim3(64,8,4), b256, 0, stream>>>(x, xbT);
    k_wcast<<<dim3(128), b256, 0, stream>>>(Wq, Wqb, 32768);
    k_wcast<<<dim3(128), b256, 0, stream>>>(Wk, Wkb, 32768);
    k_wcast<<<dim3(1024), b256, 0, stream>>>(Wv, Wvb, 262144);
    k_wcast<<<dim3(128), b256, 0, stream>>>(W_pam_out, Wpob, 32768);
    k_wcast<<<dim3(128), b256, 0, stream>>>(W_cam_out, Wcob, 32768);
    hipMemsetAsync(s0, 0, 2048*sizeof(float), stream);   // channel-sum accum
    // PAM branch
    k_wprep<<<dim3(9216), b256, 0, stream>>>(W_pam_in, wbp);
    k_conv3x3_mfma<<<dim3(32,4,4), b256, 0, stream>>>(
        xbT, wbp, pam_g, pam_b, pam_m, pam_v, feat, featTb, nullptr, 0);
    k_gemm<<<dim3(16,1,4), b256, 0, stream>>>(Wqb, featTb, bq, nullptr, qb, 64, 1);
    k_gemm<<<dim3(16,1,4), b256, 0, stream>>>(Wkb, featTb, bk, nullptr, kb, 64, 1);
    k_gemm<<<dim3(16,8,4), b256, 0, stream>>>(Wvb, featTb, bv, nullptr, vb, 512, 2);
    k_rowstats_mfma<<<dim3(64,4,2), b256, 0, stream>>>(qb, kb, rowm, rowl);
    k_pv_mfma<<<dim3(64,4,4), b256, 0, stream>>>(
        qb, kb, vb, rowm, rowl, alpha, feat, featTb);
    k_gemm<<<dim3(16,1,4), b256, 0, stream>>>(
        Wpob, featTb, b_pam_out, nullptr, pam_low, 64, 0);
    // CAM branch (reuses featTb + wbp; no fp32 feat write, sums fused)
    k_wprep<<<dim3(9216), b256, 0, stream>>>(W_cam_in, wbp);
    k_conv3x3_mfma<<<dim3(32,4,4), b256, 0, stream>>>(
        xbT, wbp, cam_g, cam_b, cam_m, cam_v, feat, featTb, s0, 1);
    k_cmlp<<<dim3(4), dim3(64), 0, stream>>>(s0, Wc1, bc1, Wc2, bc2, s2);
    k_gemm<<<dim3(16,1,4), b256, 0, stream>>>(
        Wcob, featTb, b_cam_out, s2, cam_low, 64, 0);
    // upsample + add
    k_up<<<dim3(16384), b256, 0, stream>>>(pam_low, cam_low, (float*)d_out);
}

// Round 4
// 482.183 us; speedup vs baseline: 1.5861x; 1.0012x over previous
//
#include <hip/hip_runtime.h>
#include <hip/hip_bf16.h>
#include <math.h>

#define N_  4
#define C_  512
#define H_  64
#define W_  64
#define HW_ 4096
#define CR_ 64
#define NC_ 64
#define EPSV 1e-5f

typedef __attribute__((ext_vector_type(8))) __bf16 bf16x8;
typedef __attribute__((ext_vector_type(4))) float f32x4;
typedef __hip_bfloat16 bf16s;

__device__ __forceinline__ unsigned short bfb(float f) {
    union { bf16s h; unsigned short u; } cv;
    cv.h = __float2bfloat16(f);
    return cv.u;
}

// XOR-swizzled element offset for a [64][64] bf16 LDS tile (128 B rows,
// 8 chunks of 16 B). chunk' = chunk ^ (row&7) -> conflict-free b128 access.
__device__ __forceinline__ int swz8(int row, int ch) {
    return row * 64 + ((ch ^ (row & 7)) << 3);
}

// ---------------------------------------------------------------------------
// x [n][c][hw] fp32 -> xbT [n][hw][c] bf16
// ---------------------------------------------------------------------------
__global__ __launch_bounds__(256) void k_xpose(
    const float* __restrict__ x, bf16s* __restrict__ xbT)
{
    __shared__ float xs[64][65];
    const int tid = threadIdx.x;
    const int n = blockIdx.z, c0 = blockIdx.y * 64, p0 = blockIdx.x * 64;
    for (int e = tid; e < 4096; e += 256) {
        int ci = e >> 6, pi = e & 63;
        xs[ci][pi] = x[((size_t)(n*C_ + c0 + ci))*HW_ + p0 + pi];
    }
    __syncthreads();
    for (int e = tid; e < 4096; e += 256) {
        int pi = e >> 6, ci = e & 63;
        xbT[((size_t)n*HW_ + p0 + pi)*C_ + c0 + ci] = __float2bfloat16(xs[ci][pi]);
    }
}

// w [o][c][3][3] fp32 -> wb [o][tap][c] bf16
__global__ __launch_bounds__(256) void k_wprep(
    const float* __restrict__ w, bf16s* __restrict__ wb)
{
    int e = blockIdx.x * 256 + threadIdx.x;           // < 512*9*512
    int c = e & 511; int r = e >> 9;
    int tap = r % 9; int o = r / 9;
    wb[e] = __float2bfloat16(w[((size_t)o*C_ + c)*9 + tap]);
}

// flat fp32 -> bf16 cast
__global__ __launch_bounds__(256) void k_wcast(
    const float* __restrict__ in, bf16s* __restrict__ out, int nElem)
{
    int e = blockIdx.x * 256 + threadIdx.x;
    if (e < nElem) out[e] = __float2bfloat16(in[e]);
}

// ---------------------------------------------------------------------------
// conv3x3 + BN + LReLU implicit-GEMM MFMA.
// mode 0 (PAM): writes feat fp32 [c][p] AND featT bf16 [p][c]
// mode 1 (CAM): writes featT only + atomicAdd per-channel activation sums.
// Named-register T14 prefetch (verified R3: VGPR up, scratch gone).
// ---------------------------------------------------------------------------
__global__ __launch_bounds__(256, 2) void k_conv3x3_mfma(
    const bf16s* __restrict__ xbT, const bf16s* __restrict__ wb,
    const float* __restrict__ gamma, const float* __restrict__ beta,
    const float* __restrict__ mean, const float* __restrict__ var,
    float* __restrict__ out, bf16s* __restrict__ featT,
    float* __restrict__ csum, int mode)
{
    __shared__ bf16s aL[3][128][40];
    __shared__ bf16s bL[132][40];            // [ry*66+xi][ch]
    const int tid = threadIdx.x;
    const int n  = blockIdx.z;
    const int o0 = blockIdx.y * 128;
    const int pt = blockIdx.x;
    const int y0 = pt * 2;
    const int lane = tid & 63;
    const int wid  = tid >> 6;
    const int wr = wid >> 1, wc = wid & 1;
    const int lr = lane & 15, cb = lane >> 4;

    // per-thread staging coordinates (constant across iterations)
    const int ao  = tid >> 2;                // A row within half
    const int ac  = (tid & 3) * 8;           // chunk offset (elems)
    const int t0  = tid >> 2;                // B token k=0 (ry=0, xi=t0)
    const int t1  = t0 + 64;                 // B token k=1
    const int t2  = t0 + 128;                // B token k=2 (valid if tid<16)
    const int ry1 = t1 >= 66 ? 1 : 0;
    const int xi1 = t1 - (ry1 ? 66 : 0);

    f32x4 acc[4][4];
#pragma unroll
    for (int i = 0; i < 4; ++i)
#pragma unroll
        for (int j = 0; j < 4; ++j) acc[i][j] = (f32x4){0.f,0.f,0.f,0.f};

    int4 pA0, pA1, pA2, pA3, pA4, pA5, pB0, pB1, pB2;

#define CONV_AADDR(DXI, OHALF, C0, DYI) \
    (const int4*)(wb + ((size_t)(o0 + (OHALF) + ao)*9 + (DYI)*3 + (DXI))*C_ + (C0) + ac)

#define CONV_BLOAD(DST, RY, XI, C0, DYI, VALID)                               \
    {                                                                         \
        int row_ = y0 + (DYI) - 1 + (RY);                                     \
        int xc_  = (XI) - 1;                                                  \
        int4 v_ = {0,0,0,0};                                                  \
        if ((VALID) && row_ >= 0 && row_ < H_ && xc_ >= 0 && xc_ < W_)        \
            v_ = *(const int4*)(xbT +                                         \
                ((size_t)n*HW_ + row_*W_ + xc_)*C_ + (C0) + ac);              \
        DST = v_;                                                             \
    }

#define CONV_ISSUE(C0, DYI)                                                   \
    {                                                                         \
        pA0 = *CONV_AADDR(0,  0, C0, DYI);                                    \
        pA1 = *CONV_AADDR(0, 64, C0, DYI);                                    \
        pA2 = *CONV_AADDR(1,  0, C0, DYI);                                    \
        pA3 = *CONV_AADDR(1, 64, C0, DYI);                                    \
        pA4 = *CONV_AADDR(2,  0, C0, DYI);                                    \
        pA5 = *CONV_AADDR(2, 64, C0, DYI);                                    \
        CONV_BLOAD(pB0, 0, t0, C0, DYI, 1)                                    \
        CONV_BLOAD(pB1, ry1, xi1, C0, DYI, 1)                                 \
        CONV_BLOAD(pB2, 1, t2 - 66, C0, DYI, tid < 16)                        \
    }

    CONV_ISSUE(0, 0)
    int c0 = 0, dyi = 0;
    for (int it = 0; it < 48; ++it) {
        // commit prefetched regs -> LDS (compiler inserts the vmcnt wait)
        *(int4*)&aL[0][ao][ac]      = pA0;
        *(int4*)&aL[0][64 + ao][ac] = pA1;
        *(int4*)&aL[1][ao][ac]      = pA2;
        *(int4*)&aL[1][64 + ao][ac] = pA3;
        *(int4*)&aL[2][ao][ac]      = pA4;
        *(int4*)&aL[2][64 + ao][ac] = pA5;
        *(int4*)&bL[t0][ac] = pB0;
        *(int4*)&bL[t1][ac] = pB1;
        if (tid < 16) *(int4*)&bL[t2][ac] = pB2;
        __syncthreads();                     // tiles(it) visible
        int nd = dyi + 1, nc = c0;
        if (nd == 3) { nd = 0; nc += 32; }
        if (it < 47) CONV_ISSUE(nc, nd)      // overlap with MFMA below
#pragma unroll
        for (int dxi = 0; dxi < 3; ++dxi) {
            bf16x8 af[4], bfv[4];
#pragma unroll
            for (int fm = 0; fm < 4; ++fm)
                af[fm] = *(const bf16x8*)&aL[dxi][wr*64 + fm*16 + lr][cb*8];
#pragma unroll
            for (int fn = 0; fn < 4; ++fn) {
                int pg = wc*64 + fn*16 + lr;
                int ry = pg >> 6, xc = pg & 63;
                bfv[fn] = *(const bf16x8*)&bL[ry*66 + xc + dxi][cb*8];
            }
#pragma unroll
            for (int fm = 0; fm < 4; ++fm)
#pragma unroll
                for (int fn = 0; fn < 4; ++fn)
                    acc[fm][fn] = __builtin_amdgcn_mfma_f32_16x16x32_bf16(
                        af[fm], bfv[fn], acc[fm][fn], 0, 0, 0);
        }
        __syncthreads();                     // readers(it) done
        c0 = nc; dyi = nd;
    }
#undef CONV_ISSUE
#undef CONV_BLOAD
#undef CONV_AADDR
#pragma unroll
    for (int fm = 0; fm < 4; ++fm) {
        float sc[4], sh[4];
        const int obase = o0 + wr*64 + fm*16 + cb*4;
#pragma unroll
        for (int r = 0; r < 4; ++r) {
            int o = obase + r;
            sc[r] = gamma[o] * rsqrtf(var[o] + EPSV);
            sh[r] = beta[o] - mean[o]*sc[r];
        }
        float ps[4] = {0.f, 0.f, 0.f, 0.f};
#pragma unroll
        for (int fn = 0; fn < 4; ++fn) {
            int pg = wc*64 + fn*16 + lr;
            int p  = pt*128 + pg;
            float vv[4];
#pragma unroll
            for (int r = 0; r < 4; ++r) {
                float t = fmaf(acc[fm][fn][r], sc[r], sh[r]);
                vv[r] = t > 0.f ? t : 0.2f*t;
                if (mode == 0)
                    out[((size_t)(n*C_ + obase + r))*HW_ + p] = vv[r];
                else
                    ps[r] += vv[r];
            }
            uint2 u;
            u.x = (unsigned)bfb(vv[0]) | ((unsigned)bfb(vv[1]) << 16);
            u.y = (unsigned)bfb(vv[2]) | ((unsigned)bfb(vv[3]) << 16);
            *(uint2*)&featT[((size_t)n*HW_ + p)*C_ + obase] = u;
        }
        if (mode != 0) {
            // per-channel activation sums; 16 p-lanes share channels
#pragma unroll
            for (int r = 0; r < 4; ++r) {
                float s = ps[r];
                s += __shfl_xor(s, 1);
                s += __shfl_xor(s, 2);
                s += __shfl_xor(s, 4);
                s += __shfl_xor(s, 8);
                if (lr == 0) atomicAdd(&csum[n*C_ + obase + r], s);
            }
        }
    }
}

// ---------------------------------------------------------------------------
// bf16 MFMA GEMM: out[o][p] = (A[o][:] * scale?) . Bt[p][:] + bias[o]
// mode 0: fp32 out [n][O][p]; mode 1: bf16 out [n][p][O]; mode 2: bf16 [n][O][p]
// grid (HW/256, O/64, n), block 256. Named-register T14 prefetch.
// ---------------------------------------------------------------------------
__global__ __launch_bounds__(256, 2) void k_gemm(
    const bf16s* __restrict__ A, const bf16s* __restrict__ Bt,
    const float* __restrict__ bias, const float* __restrict__ scale,
    void* __restrict__ outp, int O, int mode)
{
    __shared__ bf16s aL[64][40];
    __shared__ bf16s bL[256][40];
    const int tid = threadIdx.x;
    const int n  = blockIdx.z;
    const int p0 = blockIdx.x * 256;
    const int o0 = blockIdx.y * 64;
    const int lane = tid & 63;
    const int wid  = tid >> 6;
    const int lr = lane & 15, cb = lane >> 4;
    const int arow = tid >> 2, ach = (tid & 3) * 8;

    f32x4 acc[4][4];
#pragma unroll
    for (int i = 0; i < 4; ++i)
#pragma unroll
        for (int j = 0; j < 4; ++j) acc[i][j] = (f32x4){0.f,0.f,0.f,0.f};

    int4 pA, pB0, pB1, pB2, pB3;
    float4 pS0, pS1;

#define GEMM_ISSUE(C0)                                                        \
    {                                                                         \
        pA = *(const int4*)&A[(size_t)(o0 + arow)*C_ + (C0) + ach];           \
        if (scale) {                                                          \
            pS0 = *(const float4*)&scale[(size_t)n*C_ + (C0) + ach];          \
            pS1 = *(const float4*)&scale[(size_t)n*C_ + (C0) + ach + 4];      \
        }                                                                     \
        pB0 = *(const int4*)&Bt[((size_t)n*HW_ + p0 + arow      )*C_ + (C0) + ach]; \
        pB1 = *(const int4*)&Bt[((size_t)n*HW_ + p0 + arow +  64)*C_ + (C0) + ach]; \
        pB2 = *(const int4*)&Bt[((size_t)n*HW_ + p0 + arow + 128)*C_ + (C0) + ach]; \
        pB3 = *(const int4*)&Bt[((size_t)n*HW_ + p0 + arow + 192)*C_ + (C0) + ach]; \
    }

    GEMM_ISSUE(0)
    for (int c0 = 0; c0 < C_; c0 += 32) {
        if (scale) {
            const bf16s* sp = (const bf16s*)&pA;
            bf16s tmp[8];
            tmp[0] = __float2bfloat16(__bfloat162float(sp[0]) * pS0.x);
            tmp[1] = __float2bfloat16(__bfloat162float(sp[1]) * pS0.y);
            tmp[2] = __float2bfloat16(__bfloat162float(sp[2]) * pS0.z);
            tmp[3] = __float2bfloat16(__bfloat162float(sp[3]) * pS0.w);
            tmp[4] = __float2bfloat16(__bfloat162float(sp[4]) * pS1.x);
            tmp[5] = __float2bfloat16(__bfloat162float(sp[5]) * pS1.y);
            tmp[6] = __float2bfloat16(__bfloat162float(sp[6]) * pS1.z);
            tmp[7] = __float2bfloat16(__bfloat162float(sp[7]) * pS1.w);
            *(int4*)&aL[arow][ach] = *(int4*)tmp;
        } else {
            *(int4*)&aL[arow][ach] = pA;
        }
        *(int4*)&bL[arow      ][ach] = pB0;
        *(int4*)&bL[arow +  64][ach] = pB1;
        *(int4*)&bL[arow + 128][ach] = pB2;
        *(int4*)&bL[arow + 192][ach] = pB3;
        __syncthreads();
        if (c0 + 32 < C_) GEMM_ISSUE(c0 + 32)    // overlap with MFMA below
        bf16x8 af[4], bfv[4];
#pragma unroll
        for (int fo = 0; fo < 4; ++fo)
            af[fo] = *(const bf16x8*)&aL[fo*16 + lr][cb*8];
#pragma unroll
        for (int fp = 0; fp < 4; ++fp)
            bfv[fp] = *(const bf16x8*)&bL[wid*64 + fp*16 + lr][cb*8];
#pragma unroll
        for (int fo = 0; fo < 4; ++fo)
#pragma unroll
            for (int fp = 0; fp < 4; ++fp)
                acc[fo][fp] = __builtin_amdgcn_mfma_f32_16x16x32_bf16(
                    af[fo], bfv[fp], acc[fo][fp], 0, 0, 0);
        __syncthreads();
    }
#undef GEMM_ISSUE
#pragma unroll
    for (int fo = 0; fo < 4; ++fo) {
        const int obase = o0 + fo*16 + cb*4;
        float bv[4];
#pragma unroll
        for (int r = 0; r < 4; ++r) bv[r] = bias[obase + r];
#pragma unroll
        for (int fp = 0; fp < 4; ++fp) {
            int p = p0 + wid*64 + fp*16 + lr;
            float v[4];
#pragma unroll
            for (int r = 0; r < 4; ++r) v[r] = acc[fo][fp][r] + bv[r];
            if (mode == 1) {
                uint2 u;
                u.x = (unsigned)bfb(v[0]) | ((unsigned)bfb(v[1]) << 16);
                u.y = (unsigned)bfb(v[2]) | ((unsigned)bfb(v[3]) << 16);
                *(uint2*)&((bf16s*)outp)[((size_t)n*HW_ + p)*O + (obase - o0)] = u;
            } else if (mode == 2) {
#pragma unroll
                for (int r = 0; r < 4; ++r)
                    ((bf16s*)outp)[((size_t)(n*O + obase + r))*HW_ + p] =
                        __float2bfloat16(v[r]);
            } else {
#pragma unroll
                for (int r = 0; r < 4; ++r)
                    ((float*)outp)[((size_t)(n*O + obase + r))*HW_ + p] = v[r];
            }
        }
    }
}

// ---------------------------------------------------------------------------
// pass A: partial rowm/rowl via S^T = mfma(K, Q), j-split x2 across grid.z.
// 1-barrier/iter: double-buffered ks[2], separate qs (never overwritten).
// ---------------------------------------------------------------------------
__global__ __launch_bounds__(256) void k_rowstats_mfma(
    const bf16s* __restrict__ qb, const bf16s* __restrict__ kb,
    float* __restrict__ rowm, float* __restrict__ rowl)
{
    __shared__ bf16s qs[4096];
    __shared__ bf16s ks[2][4096];
    const int tid = threadIdx.x;
    const int lid = blockIdx.x + (blockIdx.y << 6) + (blockIdx.z << 8);
    const int n  = lid & 3;
    const int jz = (lid >> 2) & 1;
    const int i0 = (lid >> 3) << 6;
    const int lane = tid & 63;
    const int wid  = tid >> 6;
    const int lr = lane & 15, cb = lane >> 4;

    for (int e = tid; e < 512; e += 256) {
        int row = e >> 3, ch = e & 7;
        *(int4*)&qs[swz8(row, ch)] =
            *(const int4*)&qb[((size_t)n*HW_ + i0 + row)*CR_ + ch*8];
    }
    const int krow = tid >> 3, kch = tid & 7;
    const bf16s* kbase = kb + (size_t)n*HW_*CR_ + (size_t)jz*2048*CR_ + kch*8;
    int4 kreg0 = *(const int4*)(kbase + (size_t)krow*CR_);
    int4 kreg1 = *(const int4*)(kbase + (size_t)(krow + 32)*CR_);
    // commit K(0), prefetch K(1)
    *(int4*)&ks[0][swz8(krow, kch)] = kreg0;
    *(int4*)&ks[0][swz8(krow + 32, kch)] = kreg1;
    kreg0 = *(const int4*)(kbase + (size_t)(64 + krow)*CR_);
    kreg1 = *(const int4*)(kbase + (size_t)(64 + krow + 32)*CR_);
    __syncthreads();
    bf16x8 bq[2];
#pragma unroll
    for (int kk = 0; kk < 2; ++kk)
        bq[kk] = *(const bf16x8*)&qs[swz8(wid*16 + lr, kk*4 + cb)];

    float m_t = -INFINITY, l_t = 0.f;
    for (int t = 0; t < 32; ++t) {
        const bf16s* kst = ks[t & 1];
        f32x4 sv[4];
#pragma unroll
        for (int fj = 0; fj < 4; ++fj) {
            f32x4 s = (f32x4){0.f,0.f,0.f,0.f};
#pragma unroll
            for (int kk = 0; kk < 2; ++kk) {
                bf16x8 ak = *(const bf16x8*)&kst[swz8(fj*16 + lr, kk*4 + cb)];
                s = __builtin_amdgcn_mfma_f32_16x16x32_bf16(ak, bq[kk], s, 0, 0, 0);
            }
            sv[fj] = s;
        }
        if (t < 31) {                          // commit K(t+1), prefetch K(t+2)
            *(int4*)&ks[(t + 1) & 1][swz8(krow, kch)] = kreg0;
            *(int4*)&ks[(t + 1) & 1][swz8(krow + 32, kch)] = kreg1;
            if (t < 30) {
                kreg0 = *(const int4*)(kbase + (size_t)((t+2)*64 + krow)*CR_);
                kreg1 = *(const int4*)(kbase + (size_t)((t+2)*64 + krow + 32)*CR_);
            }
        }
        float mx = m_t;
#pragma unroll
        for (int fj = 0; fj < 4; ++fj)
#pragma unroll
            for (int r = 0; r < 4; ++r) mx = fmaxf(mx, sv[fj][r]);
        float sum = 0.f;
#pragma unroll
        for (int fj = 0; fj < 4; ++fj)
#pragma unroll
            for (int r = 0; r < 4; ++r) sum += __expf(sv[fj][r] - mx);
        l_t = l_t * __expf(m_t - mx) + sum;
        m_t = mx;
        __syncthreads();
    }
#pragma unroll
    for (int mask = 16; mask <= 32; mask <<= 1) {
        float mo = __shfl_xor(m_t, mask);
        float lo = __shfl_xor(l_t, mask);
        float m2 = fmaxf(m_t, mo);
        l_t = l_t * __expf(m_t - m2) + lo * __expf(mo - m2);
        m_t = m2;
    }
    if (cb == 0) {
        rowm[((size_t)jz*N_ + n)*HW_ + i0 + wid*16 + lr] = m_t;
        rowl[((size_t)jz*N_ + n)*HW_ + i0 + wid*16 + lr] = l_t;
    }
}

// ---------------------------------------------------------------------------
// pass B: block = 64 i x 128 c. 1-barrier software pipeline:
// per jt: {issue V(jt)->regs; PV(jt-1); S^T(jt)+exp->ps[jt&1];
//          ks[(jt+1)&1]<-kregs; prefetch K(jt+2); barrier}
// PV(jt-1) and S^T(jt)+exp are independent after the barrier -> MFMA/VALU
// overlap; V loads get a full iteration of latency cover (counted vmcnt).
// LDS 32 KB (ks[2]+ps[2]); 4 blk/CU. XCD-pinned n.
// ---------------------------------------------------------------------------
__global__ __launch_bounds__(256, 4) void k_pv_mfma(
    const bf16s* __restrict__ qb, const bf16s* __restrict__ kb,
    const bf16s* __restrict__ vb, const float* __restrict__ rowm,
    const float* __restrict__ rowl, const float* __restrict__ alpha,
    const float* __restrict__ feat, bf16s* __restrict__ featT)
{
    __shared__ bf16s ks[2][4096];
    __shared__ bf16s ps[2][4096];
    const int tid = threadIdx.x;
    const int lid = blockIdx.x + (blockIdx.y << 6) + (blockIdx.z << 8);
    const int k8  = lid & 7;
    const int n   = k8 >> 1;
    const int cc0 = (((lid >> 3) & 1) * 2 + (k8 & 1)) << 7;   // {0,128,256,384}
    const int i0  = (lid >> 4) << 6;
    const int lane = tid & 63;
    const int wid  = tid >> 6;
    const int lr = lane & 15, cb = lane >> 4;

    // stage Q into ks[0] (overwritten with K(0) after frag read)
    for (int e = tid; e < 512; e += 256) {
        int row = e >> 3, ch = e & 7;
        *(int4*)&ks[0][swz8(row, ch)] =
            *(const int4*)&qb[((size_t)n*HW_ + i0 + row)*CR_ + ch*8];
    }
    const int krow = tid >> 3, kch = tid & 7;
    const bf16s* kbase = kb + (size_t)n*HW_*CR_ + kch*8;
    int4 kreg0 = *(const int4*)(kbase + (size_t)krow*CR_);
    int4 kreg1 = *(const int4*)(kbase + (size_t)(krow + 32)*CR_);
    __syncthreads();                             // Q visible
    bf16x8 bq[2];                                // loop-invariant Q fragments
#pragma unroll
    for (int kk = 0; kk < 2; ++kk)
        bq[kk] = *(const bf16x8*)&ks[0][swz8(wid*16 + lr, kk*4 + cb)];

    // merge the two rowstats partials (exact online-softmax combine)
    const size_t sidx = (size_t)n*HW_ + i0 + wid*16 + lr;
    const float m0 = rowm[sidx], m1 = rowm[sidx + (size_t)N_*HW_];
    const float l0 = rowl[sidx], l1 = rowl[sidx + (size_t)N_*HW_];
    const float mreg = fmaxf(m0, m1);
    const float rinv = 1.f / (l0*__expf(m0 - mreg) + l1*__expf(m1 - mreg));
    const float al = alpha[0];
    __syncthreads();                             // Q frag reads done
    *(int4*)&ks[0][swz8(krow, kch)] = kreg0;     // commit K(0)
    *(int4*)&ks[0][swz8(krow + 32, kch)] = kreg1;
    kreg0 = *(const int4*)(kbase + (size_t)(64 + krow)*CR_);       // K(1)
    kreg1 = *(const int4*)(kbase + (size_t)(64 + krow + 32)*CR_);
    __syncthreads();                             // ks[0]=K(0) visible

    f32x4 acc[2][4];                             // [fc2][fi]
#pragma unroll
    for (int i = 0; i < 2; ++i)
#pragma unroll
        for (int j = 0; j < 4; ++j) acc[i][j] = (f32x4){0.f,0.f,0.f,0.f};

    const bf16s* vbase = vb + ((size_t)(n*C_ + cc0 + wid*32))*HW_;
    bf16x8 vc0, vc1, vc2, vc3, vn0, vn1, vn2, vn3;

    for (int jt = 0; jt < 64; ++jt) {
        // 1. issue V(jt) loads (independent; consumed next iteration)
        const bf16s* vj = vbase + jt*64;
        vn0 = *(const bf16x8*)(vj + (size_t)(     lr)*HW_      + cb*8);
        vn1 = *(const bf16x8*)(vj + (size_t)(16 + lr)*HW_      + cb*8);
        vn2 = *(const bf16x8*)(vj + (size_t)(     lr)*HW_ + 32 + cb*8);
        vn3 = *(const bf16x8*)(vj + (size_t)(16 + lr)*HW_ + 32 + cb*8);
        // 2. PV(jt-1): ps[(jt-1)&1] + vc regs (MFMA-only, overlaps step 3)
        if (jt > 0) {
            const bf16s* pp = ps[(jt - 1) & 1];
            bf16x8 pa[4];
#pragma unroll
            for (int fi = 0; fi < 4; ++fi)
                pa[fi] = *(const bf16x8*)&pp[swz8(fi*16 + lr, cb)];
#pragma unroll
            for (int fi = 0; fi < 4; ++fi) {
                acc[0][fi] = __builtin_amdgcn_mfma_f32_16x16x32_bf16(
                    vc0, pa[fi], acc[0][fi], 0, 0, 0);
                acc[1][fi] = __builtin_amdgcn_mfma_f32_16x16x32_bf16(
                    vc1, pa[fi], acc[1][fi], 0, 0, 0);
            }
#pragma unroll
            for (int fi = 0; fi < 4; ++fi)
                pa[fi] = *(const bf16x8*)&pp[swz8(fi*16 + lr, 4 + cb)];
#pragma unroll
            for (int fi = 0; fi < 4; ++fi) {
                acc[0][fi] = __builtin_amdgcn_mfma_f32_16x16x32_bf16(
                    vc2, pa[fi], acc[0][fi], 0, 0, 0);
                acc[1][fi] = __builtin_amdgcn_mfma_f32_16x16x32_bf16(
                    vc3, pa[fi], acc[1][fi], 0, 0, 0);
            }
        }
        // 3. S^T(jt) from ks[jt&1] + exp -> ps[jt&1]
        {
            const bf16s* kst = ks[jt & 1];
            bf16s* pst = ps[jt & 1];
#pragma unroll
            for (int fj = 0; fj < 4; ++fj) {
                f32x4 s = (f32x4){0.f,0.f,0.f,0.f};
#pragma unroll
                for (int kk = 0; kk < 2; ++kk) {
                    bf16x8 ak = *(const bf16x8*)&kst[swz8(fj*16 + lr, kk*4 + cb)];
                    s = __builtin_amdgcn_mfma_f32_16x16x32_bf16(ak, bq[kk], s, 0, 0, 0);
                }
                unsigned short b[4];
#pragma unroll
                for (int r = 0; r < 4; ++r)
                    b[r] = bfb(__expf(s[r] - mreg) * rinv);
                uint2 u;
                u.x = (unsigned)b[0] | ((unsigned)b[1] << 16);
                u.y = (unsigned)b[2] | ((unsigned)b[3] << 16);
                *(uint2*)&pst[swz8(wid*16 + lr, fj*2 + (cb >> 1)) + (cb & 1)*4] = u;
            }
        }
        // 4. commit K(jt+1), prefetch K(jt+2)
        if (jt < 63) {
            *(int4*)&ks[(jt + 1) & 1][swz8(krow, kch)] = kreg0;
            *(int4*)&ks[(jt + 1) & 1][swz8(krow + 32, kch)] = kreg1;
            if (jt < 62) {
                kreg0 = *(const int4*)(kbase + (size_t)((jt+2)*64 + krow)*CR_);
                kreg1 = *(const int4*)(kbase + (size_t)((jt+2)*64 + krow + 32)*CR_);
            }
        }
        // 5. rotate V regs
        vc0 = vn0; vc1 = vn1; vc2 = vn2; vc3 = vn3;
        __syncthreads();
    }
    // epilogue PV(63)
    {
        const bf16s* pp = ps[63 & 1];
        bf16x8 pa[4];
#pragma unroll
        for (int fi = 0; fi < 4; ++fi)
            pa[fi] = *(const bf16x8*)&pp[swz8(fi*16 + lr, cb)];
#pragma unroll
        for (int fi = 0; fi < 4; ++fi) {
            acc[0][fi] = __builtin_amdgcn_mfma_f32_16x16x32_bf16(
                vc0, pa[fi], acc[0][fi], 0, 0, 0);
            acc[1][fi] = __builtin_amdgcn_mfma_f32_16x16x32_bf16(
                vc1, pa[fi], acc[1][fi], 0, 0, 0);
        }
#pragma unroll
        for (int fi = 0; fi < 4; ++fi)
            pa[fi] = *(const bf16x8*)&pp[swz8(fi*16 + lr, 4 + cb)];
#pragma unroll
        for (int fi = 0; fi < 4; ++fi) {
            acc[0][fi] = __builtin_amdgcn_mfma_f32_16x16x32_bf16(
                vc2, pa[fi], acc[0][fi], 0, 0, 0);
            acc[1][fi] = __builtin_amdgcn_mfma_f32_16x16x32_bf16(
                vc3, pa[fi], acc[1][fi], 0, 0, 0);
        }
    }
    // epilogue: residual add + bf16, direct uint2 stores
#pragma unroll
    for (int fc2 = 0; fc2 < 2; ++fc2) {
        const int ccl = wid*32 + fc2*16 + cb*4;
#pragma unroll
        for (int fi = 0; fi < 4; ++fi) {
            const int p = i0 + fi*16 + lr;
            const float* fp = &feat[((size_t)(n*C_ + cc0 + ccl))*HW_ + p];
            float v0 = fmaf(al, acc[fc2][fi][0], fp[0]);
            float v1 = fmaf(al, acc[fc2][fi][1], fp[(size_t)HW_]);
            float v2 = fmaf(al, acc[fc2][fi][2], fp[(size_t)2*HW_]);
            float v3 = fmaf(al, acc[fc2][fi][3], fp[(size_t)3*HW_]);
            uint2 u;
            u.x = (unsigned)bfb(v0) | ((unsigned)bfb(v1) << 16);
            u.y = (unsigned)bfb(v2) | ((unsigned)bfb(v3) << 16);
            *(uint2*)&featT[((size_t)n*HW_ + p)*C_ + cc0 + ccl] = u;
        }
    }
}

// ---------------------------------------------------------------------------
__global__ __launch_bounds__(64) void k_cmlp(
    const float* __restrict__ s0, const float* __restrict__ Wc1,
    const float* __restrict__ bc1, const float* __restrict__ Wc2,
    const float* __restrict__ bc2, float* __restrict__ s2)
{
    const int n = blockIdx.x, tid = threadIdx.x;
    __shared__ float s1s[64];
    float a = 0.f;
    for (int c = 0; c < C_; ++c)
        a = fmaf(Wc1[(size_t)tid*C_ + c], s0[n*C_ + c] * (1.f/HW_), a);
    a += bc1[tid];
    a = a > 0.f ? a : 0.2f*a;
    s1s[tid] = a;
    __syncthreads();
    for (int c = tid; c < C_; c += 64) {
        float b = 0.f;
        for (int i = 0; i < CR_; ++i) b = fmaf(Wc2[(size_t)c*CR_ + i], s1s[i], b);
        b += bc2[c];
        s2[n*C_ + c] = 1.f / (1.f + __expf(-b));
    }
}

__global__ __launch_bounds__(256) void k_up(
    const float* __restrict__ pl, const float* __restrict__ cl,
    float* __restrict__ out)
{
    int idx = blockIdx.x * 256 + threadIdx.x;
    int ox = idx & 127; int rest = idx >> 7;
    int oy = rest & 127; rest >>= 7;
    int o  = rest & 63;  int n = rest >> 6;
    float fy = oy*0.5f - 0.25f;
    float fx = ox*0.5f - 0.25f;
    int y0 = (int)floorf(fy); float wy = fy - y0;
    int x0 = (int)floorf(fx); float wx = fx - x0;
    int y0c = y0 < 0 ? 0 : y0;      int y1c = y0+1 > 63 ? 63 : y0+1;
    int x0c = x0 < 0 ? 0 : x0;      int x1c = x0+1 > 63 ? 63 : x0+1;
    const float* a = pl + ((size_t)(n*NC_ + o))*HW_;
    const float* b = cl + ((size_t)(n*NC_ + o))*HW_;
    float v00 = a[y0c*64+x0c] + b[y0c*64+x0c];
    float v01 = a[y0c*64+x1c] + b[y0c*64+x1c];
    float v10 = a[y1c*64+x0c] + b[y1c*64+x0c];
    float v11 = a[y1c*64+x1c] + b[y1c*64+x1c];
    out[idx] = (1.f-wy)*((1.f-wx)*v00 + wx*v01) + wy*((1.f-wx)*v10 + wx*v11);
}

// ---------------------------------------------------------------------------
extern "C" void kernel_launch(void* const* d_in, const int* in_sizes, int n_in,
                              void* d_out, int out_size, void* d_ws, size_t ws_size,
                              hipStream_t stream)
{
    const float* x         = (const float*)d_in[0];
    const float* W_pam_in  = (const float*)d_in[1];
    const float* pam_g     = (const float*)d_in[2];
    const float* pam_b     = (const float*)d_in[3];
    const float* pam_m     = (const float*)d_in[4];
    const float* pam_v     = (const float*)d_in[5];
    const float* Wq        = (const float*)d_in[6];
    const float* bq        = (const float*)d_in[7];
    const float* Wk        = (const float*)d_in[8];
    const float* bk        = (const float*)d_in[9];
    const float* Wv        = (const float*)d_in[10];
    const float* bv        = (const float*)d_in[11];
    const float* alpha     = (const float*)d_in[12];
    const float* W_pam_out = (const float*)d_in[13];
    const float* b_pam_out = (const float*)d_in[14];
    const float* W_cam_in  = (const float*)d_in[15];
    const float* cam_g     = (const float*)d_in[16];
    const float* cam_b     = (const float*)d_in[17];
    const float* cam_m     = (const float*)d_in[18];
    const float* cam_v     = (const float*)d_in[19];
    const float* Wc1       = (const float*)d_in[20];
    const float* bc1       = (const float*)d_in[21];
    const float* Wc2       = (const float*)d_in[22];
    const float* bc2       = (const float*)d_in[23];
    const float* W_cam_out = (const float*)d_in[24];
    const float* b_cam_out = (const float*)d_in[25];

    float* feat    = (float*)d_ws;             // [4][512][4096] fp32
    float* pam_low = feat    + 8388608;        // [4][64][4096]
    float* rowm    = pam_low + 1048576;        // [2][4][4096] partials
    float* rowl    = rowm    + 32768;          // [2][4][4096]
    float* s0      = rowl    + 32768;          // [4][512]
    float* s2      = s0      + 2048;
    bf16s* xbT     = (bf16s*)(s2 + 2048);      // [4][4096][512] bf16
    bf16s* featTb  = xbT + 8388608;            // [4][4096][512]
    bf16s* vb      = featTb + 8388608;         // [4][512][4096]
    bf16s* qb      = vb + 8388608;             // [4][4096][64]
    bf16s* kb      = qb + 1048576;
    bf16s* wbp     = kb + 1048576;             // [512][9][512] (shared pam/cam)
    bf16s* Wqb     = wbp + 2359296;            // [64][512]
    bf16s* Wkb     = Wqb + 32768;
    bf16s* Wvb     = Wkb + 32768;              // [512][512]
    bf16s* Wpob    = Wvb + 262144;             // [64][512]
    bf16s* Wcob    = Wpob + 32768;             // [64][512]
    float* cam_low = (float*)qb;               // aliases qb+kb (dead after k_pv)

    dim3 b256(256);
    k_xpose<<<dim3(64,8,4), b256, 0, stream>>>(x, xbT);
    k_wcast<<<dim3(128), b256, 0, stream>>>(Wq, Wqb, 32768);
    k_wcast<<<dim3(128), b256, 0, stream>>>(Wk, Wkb, 32768);
    k_wcast<<<dim3(1024), b256, 0, stream>>>(Wv, Wvb, 262144);
    k_wcast<<<dim3(128), b256, 0, stream>>>(W_pam_out, Wpob, 32768);
    k_wcast<<<dim3(128), b256, 0, stream>>>(W_cam_out, Wcob, 32768);
    hipMemsetAsync(s0, 0, 2048*sizeof(float), stream);   // channel-sum accum
    // PAM branch
    k_wprep<<<dim3(9216), b256, 0, stream>>>(W_pam_in, wbp);
    k_conv3x3_mfma<<<dim3(32,4,4), b256, 0, stream>>>(
        xbT, wbp, pam_g, pam_b, pam_m, pam_v, feat, featTb, nullptr, 0);
    k_gemm<<<dim3(16,1,4), b256, 0, stream>>>(Wqb, featTb, bq, nullptr, qb, 64, 1);
    k_gemm<<<dim3(16,1,4), b256, 0, stream>>>(Wkb, featTb, bk, nullptr, kb, 64, 1);
    k_gemm<<<dim3(16,8,4), b256, 0, stream>>>(Wvb, featTb, bv, nullptr, vb, 512, 2);
    k_rowstats_mfma<<<dim3(64,4,2), b256, 0, stream>>>(qb, kb, rowm, rowl);
    k_pv_mfma<<<dim3(64,4,4), b256, 0, stream>>>(
        qb, kb, vb, rowm, rowl, alpha, feat, featTb);
    k_gemm<<<dim3(16,1,4), b256, 0, stream>>>(
        Wpob, featTb, b_pam_out, nullptr, pam_low, 64, 0);
    // CAM branch (reuses featTb + wbp; no fp32 feat write, sums fused)
    k_wprep<<<dim3(9216), b256, 0, stream>>>(W_cam_in, wbp);
    k_conv3x3_mfma<<<dim3(32,4,4), b256, 0, stream>>>(
        xbT, wbp, cam_g, cam_b, cam_m, cam_v, feat, featTb, s0, 1);
    k_cmlp<<<dim3(4), dim3(64), 0, stream>>>(s0, Wc1, bc1, Wc2, bc2, s2);
    k_gemm<<<dim3(16,1,4), b256, 0, stream>>>(
        Wcob, featTb, b_cam_out, s2, cam_low, 64, 0);
    // upsample + add
    k_up<<<dim3(16384), b256, 0, stream>>>(pam_low, cam_low, (float*)d_out);
}